// Round 6
// baseline (222.985 us; speedup 1.0000x reference)
//
#include <hip/hip_runtime.h>
#include <hip/hip_bf16.h>
#include <cstdint>

#define T_DIM 2048
#define C_DIM 256
#define BS 8
#define NPTS (BS * T_DIM)
#define KNB 10

typedef __bf16 bf16x8 __attribute__((ext_vector_type(8)));
typedef float f32x4 __attribute__((ext_vector_type(4)));

#define AS1 __attribute__((address_space(1)))
#define AS3 __attribute__((address_space(3)))

__device__ __forceinline__ unsigned short f2bf_rn(float f) {
  unsigned u = __float_as_uint(f);
  unsigned r = (u + 0x7FFFu + ((u >> 16) & 1u)) >> 16;
  return (unsigned short)r;
}
__device__ __forceinline__ float bfbits2f(unsigned short h) {
  return __uint_as_float((unsigned)h << 16);
}
__device__ __forceinline__ __bf16 bfbits(unsigned short h) {
  return __builtin_bit_cast(__bf16, h);
}

// pinned dif computation: identical instruction sequence at every use site so
// phase-1 keys, theta, count keys, and fallback keys are bit-identical.
__device__ __forceinline__ unsigned key_hi(float sqi, float sqj, float gv) {
  float dif = __fmaf_rn(-2.0f, gv, __fadd_rn(sqi, sqj));
  unsigned u = __float_as_uint(dif);
  return (u & 0x80000000u) ? ~u : (u | 0x80000000u);
}

// ---- stage a 128x64 bf16 tile into XOR-swizzled LDS via global_load_lds ----
__device__ __forceinline__ void stage_tile(const __bf16* __restrict__ src, size_t row0,
                                           int ld, int k0, __bf16* lds, int w, int l) {
  int kofs = ((l & 7) ^ (l >> 3)) * 8;
  const __bf16* g0 = src + (row0 + (size_t)(l >> 3)) * ld + k0 + kofs;
  __bf16* lbase = lds + (size_t)(w * 4) * 512;
#pragma unroll
  for (int q4 = 0; q4 < 4; ++q4) {
    __builtin_amdgcn_global_load_lds((AS1 void*)(g0 + (size_t)(w * 4 + q4) * 8 * ld),
                                     (AS3 void*)(lbase + q4 * 512), 16, 0, 0);
  }
}

// conv im2col staging: K=768 = 3 taps x 256
__device__ __forceinline__ void stage_tile_conv(const __bf16* __restrict__ src, int m0,
                                                int k0in, const __bf16* __restrict__ zp,
                                                __bf16* lds, int w, int l) {
  int tap = k0in >> 8;
  int kshift = tap - 1;
  int k0 = k0in & 255;
  int kofs = ((l & 7) ^ (l >> 3)) * 8;
  int mb = m0 & (T_DIM - 1);
#pragma unroll
  for (int q4 = 0; q4 < 4; ++q4) {
    int q = w * 4 + q4;
    int row = q * 8 + (l >> 3);
    int t = mb + row + kshift;
    const __bf16* g = ((unsigned)t < (unsigned)T_DIM)
                          ? (src + (size_t)(m0 + row + kshift) * C_DIM + k0 + kofs)
                          : (zp + kofs);
    __builtin_amdgcn_global_load_lds((AS1 void*)g, (AS3 void*)(lds + q * 512), 16, 0, 0);
  }
}

__device__ __forceinline__ bf16x8 read_frag(const __bf16* lds, int t16, int ks, int l) {
  int row = t16 * 16 + (l & 15);
  int kb = ks * 64 + ((l >> 4) << 4);
  int byte = row * 128 + (kb ^ ((row & 7) << 4));
  return *(const bf16x8*)((const char*)lds + byte);
}

// ---------------- transpose + hi/lo bf16 split ----------------
__global__ __launch_bounds__(256) void k_transpose_split(const float* __restrict__ x,
                                                         __bf16* __restrict__ Fh,
                                                         __bf16* __restrict__ Fl) {
  __shared__ float tile[32][33];
  int b = blockIdx.z;
  int t0 = blockIdx.x * 32;
  int c0 = blockIdx.y * 32;
  int tx = threadIdx.x & 31, ty = threadIdx.x >> 5;
  const float* xb = x + (size_t)b * C_DIM * T_DIM;
#pragma unroll
  for (int r = 0; r < 4; ++r) {
    int c = c0 + ty + 8 * r;
    tile[ty + 8 * r][tx] = xb[(size_t)c * T_DIM + t0 + tx];
  }
  __syncthreads();
#pragma unroll
  for (int r = 0; r < 4; ++r) {
    int t = t0 + ty + 8 * r;
    float v = tile[tx][ty + 8 * r];
    unsigned short hb = f2bf_rn(v);
    float lo = v - bfbits2f(hb);
    size_t o = ((size_t)b * T_DIM + t) * C_DIM + c0 + tx;
    Fh[o] = bfbits(hb);
    Fl[o] = bfbits(f2bf_rn(lo));
  }
}

// ---------------- sq[n] = sum_c (hi+lo)^2 ----------------
__global__ __launch_bounds__(256) void k_sq(const __bf16* __restrict__ Fh,
                                            const __bf16* __restrict__ Fl,
                                            float* __restrict__ sq) {
  int n = blockIdx.x * 4 + (threadIdx.x >> 6);
  int lane = threadIdx.x & 63;
  ushort4 hv = ((const ushort4*)Fh)[(size_t)n * 64 + lane];
  ushort4 lv = ((const ushort4*)Fl)[(size_t)n * 64 + lane];
  float s = 0.f;
  {
    float v;
    v = bfbits2f(hv.x) + bfbits2f(lv.x); s = fmaf(v, v, s);
    v = bfbits2f(hv.y) + bfbits2f(lv.y); s = fmaf(v, v, s);
    v = bfbits2f(hv.z) + bfbits2f(lv.z); s = fmaf(v, v, s);
    v = bfbits2f(hv.w) + bfbits2f(lv.w); s = fmaf(v, v, s);
  }
#pragma unroll
  for (int d = 1; d < 64; d <<= 1) s += __shfl_xor(s, d, 64);
  if (lane == 0) sq[n] = s;
}

// ---------------- Gram via split-bf16 MFMA, symmetric ----------------
__global__ __launch_bounds__(256, 2) void k_gram_sym(const __bf16* __restrict__ Fh,
                                                     const __bf16* __restrict__ Fl,
                                                     float* __restrict__ gram) {
  __shared__ __align__(16) char smem[65536];
  __bf16* Ah = (__bf16*)smem;
  __bf16* Al = (__bf16*)(smem + 16384);
  __bf16* Bh = (__bf16*)(smem + 32768);
  __bf16* Bl = (__bf16*)(smem + 49152);

  int b = blockIdx.y;
  int ti = blockIdx.x;
  int by = (int)((sqrtf(8.0f * (float)ti + 1.0f) - 1.0f) * 0.5f);
  if ((by + 1) * (by + 2) / 2 <= ti) by++;
  int bx = ti - by * (by + 1) / 2;

  size_t base = (size_t)b * T_DIM;
  int m0 = by * 128, n0 = bx * 128;
  int tid = threadIdx.x, w = tid >> 6, l = tid & 63;
  int wr = w >> 1, wc = w & 1;
  f32x4 acc[4][4];
#pragma unroll
  for (int i = 0; i < 4; ++i)
#pragma unroll
    for (int j = 0; j < 4; ++j) acc[i][j] = {0.f, 0.f, 0.f, 0.f};

  for (int k0 = 0; k0 < C_DIM; k0 += 64) {
    stage_tile(Fh, base + m0, C_DIM, k0, Ah, w, l);
    stage_tile(Fl, base + m0, C_DIM, k0, Al, w, l);
    stage_tile(Fh, base + n0, C_DIM, k0, Bh, w, l);
    stage_tile(Fl, base + n0, C_DIM, k0, Bl, w, l);
    __syncthreads();
#pragma unroll
    for (int ks = 0; ks < 2; ++ks) {
      bf16x8 ah[4], bh[4], x[4];
#pragma unroll
      for (int i = 0; i < 4; ++i) ah[i] = read_frag(Ah, wr * 4 + i, ks, l);
#pragma unroll
      for (int j = 0; j < 4; ++j) bh[j] = read_frag(Bh, wc * 4 + j, ks, l);
#pragma unroll
      for (int i = 0; i < 4; ++i)
#pragma unroll
        for (int j = 0; j < 4; ++j)
          acc[i][j] = __builtin_amdgcn_mfma_f32_16x16x32_bf16(ah[i], bh[j], acc[i][j], 0, 0, 0);
#pragma unroll
      for (int i = 0; i < 4; ++i) x[i] = read_frag(Al, wr * 4 + i, ks, l);
#pragma unroll
      for (int i = 0; i < 4; ++i)
#pragma unroll
        for (int j = 0; j < 4; ++j)
          acc[i][j] = __builtin_amdgcn_mfma_f32_16x16x32_bf16(x[i], bh[j], acc[i][j], 0, 0, 0);
#pragma unroll
      for (int j = 0; j < 4; ++j) x[j] = read_frag(Bl, wc * 4 + j, ks, l);
#pragma unroll
      for (int i = 0; i < 4; ++i)
#pragma unroll
        for (int j = 0; j < 4; ++j)
          acc[i][j] = __builtin_amdgcn_mfma_f32_16x16x32_bf16(ah[i], x[j], acc[i][j], 0, 0, 0);
    }
    __syncthreads();
  }

  float* gout = gram + (size_t)b * T_DIM * T_DIM;
#pragma unroll
  for (int i = 0; i < 4; ++i) {
    int mrow = m0 + wr * 64 + i * 16 + ((l >> 4) << 2);
#pragma unroll
    for (int j = 0; j < 4; ++j) {
      int ncol = n0 + wc * 64 + j * 16 + (l & 15);
      float* cp = gout + (size_t)mrow * T_DIM + ncol;
#pragma unroll
      for (int r = 0; r < 4; ++r) cp[(size_t)r * T_DIM] = acc[i][j][r];
    }
  }

  if (bx != by) {
    float* Tbuf = (float*)smem;
#pragma unroll
    for (int h = 0; h < 2; ++h) {
      __syncthreads();
      if (wc == h) {
#pragma unroll
        for (int j = 0; j < 4; ++j) {
          int cH = j * 16 + (l & 15);
          float* dst = Tbuf + cH * 132 + wr * 64 + ((l >> 4) << 2);
#pragma unroll
          for (int i = 0; i < 4; ++i) *(f32x4*)(dst + i * 16) = acc[i][j];
        }
      }
      __syncthreads();
      int cH = tid >> 5;
      int c4 = (tid & 31) * 4;
#pragma unroll
      for (int p = 0; p < 8; ++p) {
        f32x4 v = *(const f32x4*)(Tbuf + (size_t)(p * 8 + cH) * 132 + c4);
        *(f32x4*)(gout + (size_t)(n0 + h * 64 + p * 8 + cH) * T_DIM + m0 + c4) = v;
      }
    }
  }
}

// ---------------- plain bf16 GEMM C = A.B^T ----------------
__global__ __launch_bounds__(256, 2) void k_gemm16(const __bf16* __restrict__ A,
                                                   const __bf16* __restrict__ Bm,
                                                   float* __restrict__ C, int N, int K,
                                                   int conv, const __bf16* __restrict__ zp) {
  __shared__ __bf16 As[128 * 64], Bs[128 * 64];
  int m0 = blockIdx.y * 128, n0 = blockIdx.x * 128;
  int tid = threadIdx.x, w = tid >> 6, l = tid & 63;
  int wr = w >> 1, wc = w & 1;
  f32x4 acc[4][4];
#pragma unroll
  for (int i = 0; i < 4; ++i)
#pragma unroll
    for (int j = 0; j < 4; ++j) acc[i][j] = {0.f, 0.f, 0.f, 0.f};

  for (int k0 = 0; k0 < K; k0 += 64) {
    if (conv)
      stage_tile_conv(A, m0, k0, zp, As, w, l);
    else
      stage_tile(A, (size_t)m0, C_DIM, k0, As, w, l);
    stage_tile(Bm, (size_t)n0, K, k0, Bs, w, l);
    __syncthreads();
#pragma unroll
    for (int ks = 0; ks < 2; ++ks) {
      bf16x8 af[4], bf_[4];
#pragma unroll
      for (int i = 0; i < 4; ++i) af[i] = read_frag(As, wr * 4 + i, ks, l);
#pragma unroll
      for (int j = 0; j < 4; ++j) bf_[j] = read_frag(Bs, wc * 4 + j, ks, l);
#pragma unroll
      for (int i = 0; i < 4; ++i)
#pragma unroll
        for (int j = 0; j < 4; ++j)
          acc[i][j] = __builtin_amdgcn_mfma_f32_16x16x32_bf16(af[i], bf_[j], acc[i][j], 0, 0, 0);
    }
    __syncthreads();
  }
#pragma unroll
  for (int i = 0; i < 4; ++i) {
    int mrow = m0 + wr * 64 + i * 16 + ((l >> 4) << 2);
#pragma unroll
    for (int j = 0; j < 4; ++j) {
      int ncol = n0 + wc * 64 + j * 16 + (l & 15);
      float* cp = C + (size_t)mrow * N + ncol;
#pragma unroll
      for (int r = 0; r < 4; ++r) cp[(size_t)r * N] = acc[i][j][r];
    }
  }
}

// ---------------- per-row top-10: stashless min-2 filter + L2 re-read verify ----------------
// Key semantics identical to R3-R5: u64 key = (flip32(dif) << 32) | j, with dif pinned
// to __fmaf_rn(-2, g, __fadd_rn(sqi, sqj)) at EVERY use site (bit-identical phases).
// No per-thread stash => ~40 VGPRs => high occupancy; phase 3 / fallback re-read the
// gram row (L2-resident: ~4 MB active rows per XCD).
__global__ __launch_bounds__(256) void k_topk(const float* __restrict__ gram,
                                              const float* __restrict__ sq,
                                              int* __restrict__ idxo,
                                              float* __restrict__ wo) {
  int lb = blockIdx.y;
  const float* gramb = gram + (size_t)lb * T_DIM * T_DIM;
  const float* sqb = sq + (size_t)lb * T_DIM;
  int* idxb = idxo + (size_t)lb * T_DIM * KNB;
  float* wbp = wo + (size_t)lb * T_DIM * KNB;

  int row = blockIdx.x * 4 + (threadIdx.x >> 6);
  int lane = threadIdx.x & 63;
  float sqi = sqb[row];
  const float* g = gramb + (size_t)row * T_DIM;

  // Phase 1: 4 independent u64 min-2 trackers (ILP), no stash
  unsigned long long p0[4], p1[4];
#pragma unroll
  for (int q = 0; q < 4; ++q) { p0[q] = ~0ull; p1[q] = ~0ull; }
#pragma unroll
  for (int t = 0; t < 32; ++t) {
    int q = t & 3;
    int j = lane + 64 * t;
    unsigned u = key_hi(sqi, sqb[j], g[j]);
    unsigned long long key = ((unsigned long long)u << 32) | (unsigned)j;
    unsigned long long mx = (key > p0[q]) ? key : p0[q];
    p0[q] = (key < p0[q]) ? key : p0[q];
    p1[q] = (mx < p1[q]) ? mx : p1[q];
  }
  // exact merge of 4 min-2 pairs -> per-lane min-2 (m0, m1)
  unsigned long long m0 = p0[0], m1 = p1[0];
#pragma unroll
  for (int q = 1; q < 4; ++q) {
    unsigned long long k0 = p0[q], k1 = p1[q];
    unsigned long long mx = (k0 > m0) ? k0 : m0;
    m0 = (k0 < m0) ? k0 : m0;
    m1 = (mx < m1) ? mx : m1;
    m1 = (k1 < m1) ? k1 : m1;  // k1 >= k0, can only land in second slot
  }

  // Phase 2: 10-round wave extract-min over the 128 candidates; write results
  unsigned long long theta = 0;
#pragma unroll
  for (int s = 0; s < KNB; ++s) {
    unsigned long long m = m0;
#pragma unroll
    for (int d = 1; d < 64; d <<= 1) {
      unsigned long long o = __shfl_xor(m, d, 64);
      m = (o < m) ? o : m;
    }
    unsigned long long bal = __ballot(m0 == m);
    int leader = (int)__builtin_ctzll(bal);
    if (lane == leader) { m0 = m1; m1 = ~0ull; }
    if (lane == 0) {
      int j = (int)(unsigned)(m & 0xffffffffull);
      unsigned su = (unsigned)(m >> 32);
      unsigned bits = (su & 0x80000000u) ? (su & 0x7fffffffu) : ~su;
      float dif = __uint_as_float(bits);
      float sqj = sqb[j];
      float num = 0.5f * (sqi + sqj - dif);
      float wv = num / (sqrtf(sqi) * sqrtf(sqj));
      idxb[row * KNB + s] = j;
      wbp[row * KNB + s] = wv;
    }
    theta = m;
  }

  // Phase 3: exact strict-order count vs theta, re-reading the row (L2-hot)
  unsigned thi = (unsigned)(theta >> 32);
  unsigned tlo = (unsigned)(theta & 0xffffffffull);
  int c = 0;
#pragma unroll
  for (int t = 0; t < 32; ++t) {
    unsigned j = (unsigned)(lane + 64 * t);
    unsigned u = key_hi(sqi, sqb[j], g[j]);
    c += (u < thi) || ((u == thi) && (j < tlo));
  }
#pragma unroll
  for (int d = 1; d < 64; d <<= 1) c += __shfl_xor(c, d, 64);

  if (c == 9) return;  // provably exact (wave-uniform)

  // Fallback (rare): full sorted-10 insert re-reading the row, then re-extract.
  unsigned long long b0 = ~0ull, b1 = ~0ull, b2 = ~0ull, b3 = ~0ull, b4 = ~0ull,
                     b5 = ~0ull, b6 = ~0ull, b7 = ~0ull, b8 = ~0ull, b9 = ~0ull;
  for (int t = 0; t < 32; ++t) {
    unsigned j = (unsigned)(lane + 64 * t);
    unsigned u = key_hi(sqi, sqb[j], g[j]);
    unsigned long long key = ((unsigned long long)u << 32) | j;
    if (key < b9) {
      b9 = key;
      unsigned long long tt;
      if (b9 < b8) { tt = b8; b8 = b9; b9 = tt; }
      if (b8 < b7) { tt = b7; b7 = b8; b8 = tt; }
      if (b7 < b6) { tt = b6; b6 = b7; b7 = tt; }
      if (b6 < b5) { tt = b5; b5 = b6; b6 = tt; }
      if (b5 < b4) { tt = b4; b4 = b5; b5 = tt; }
      if (b4 < b3) { tt = b3; b3 = b4; b4 = tt; }
      if (b3 < b2) { tt = b2; b2 = b3; b3 = tt; }
      if (b2 < b1) { tt = b1; b1 = b2; b2 = tt; }
      if (b1 < b0) { tt = b0; b0 = b1; b1 = tt; }
    }
  }
#pragma unroll
  for (int s = 0; s < KNB; ++s) {
    unsigned long long m = b0;
#pragma unroll
    for (int d = 1; d < 64; d <<= 1) {
      unsigned long long o = __shfl_xor(m, d, 64);
      m = (o < m) ? o : m;
    }
    unsigned long long bal = __ballot(b0 == m);
    int leader = (int)__builtin_ctzll(bal);
    if (lane == leader) {
      b0 = b1; b1 = b2; b2 = b3; b3 = b4; b4 = b5;
      b5 = b6; b6 = b7; b7 = b8; b8 = b9; b9 = ~0ull;
    }
    if (lane == 0) {
      int j = (int)(unsigned)(m & 0xffffffffull);
      unsigned su = (unsigned)(m >> 32);
      unsigned bits = (su & 0x80000000u) ? (su & 0x7fffffffu) : ~su;
      float dif = __uint_as_float(bits);
      float sqj = sqb[j];
      float num = 0.5f * (sqi + sqj - dif);
      float wv = num / (sqrtf(sqi) * sqrtf(sqj));
      idxb[row * KNB + s] = j;
      wbp[row * KNB + s] = wv;
    }
  }
}

// ---------------- fused gmax + conv-bias + relu + pairwise maxpool + transpose ----------------
__global__ __launch_bounds__(256) void k_gfinal(const float* __restrict__ mlpout,
                                                const float* __restrict__ mlp_b,
                                                const int* __restrict__ idxo,
                                                const float* __restrict__ wo,
                                                const float* __restrict__ convb,
                                                const float* __restrict__ cb,
                                                float* __restrict__ out) {
  __shared__ float tile[32][33];
  __shared__ int sj[64][KNB];
  __shared__ float sw[64][KNB];
  int b = blockIdx.z, c0 = blockIdx.y * 32, t20 = blockIdx.x * 32;
  int tid = threadIdx.x;
  int nbase = b * T_DIM + t20 * 2;
  for (int e = tid; e < 64 * KNB; e += 256) {
    int ln = e / KNB, k = e - ln * KNB;
    sj[ln][k] = b * T_DIM + idxo[(size_t)(nbase + ln) * KNB + k];
    sw[ln][k] = wo[(size_t)(nbase + ln) * KNB + k];
  }
  __syncthreads();
  int tx = tid & 31, ty = tid >> 5;
  int c = c0 + tx;
  float bias_c = cb[c];
  float mbias = mlp_b[c];
#pragma unroll
  for (int rr = 0; rr < 4; ++rr) {
    int lt2 = ty + 8 * rr;
    float res[2];
#pragma unroll
    for (int s = 0; s < 2; ++s) {
      int ln = 2 * lt2 + s;
      int n = nbase + ln;
      float q = mlpout[(size_t)n * 512 + 256 + c] + mbias;
      float mx = -3.4e38f;
#pragma unroll
      for (int k = 0; k < KNB; ++k) {
        float v = (mlpout[(size_t)sj[ln][k] * 512 + c] + q) * sw[ln][k];
        mx = fmaxf(mx, v);
      }
      float v = convb[(size_t)n * C_DIM + c] + mx + bias_c;
      res[s] = fmaxf(v, 0.f);
    }
    tile[lt2][tx] = fmaxf(res[0], res[1]);
  }
  __syncthreads();
#pragma unroll
  for (int rr = 0; rr < 4; ++rr) {
    int cc = c0 + ty + 8 * rr;
    out[((size_t)b * C_DIM + cc) * (T_DIM / 2) + t20 + tx] = tile[tx][ty + 8 * rr];
  }
}

// ---------------- merged repack ----------------
__global__ void k_repack(const float* __restrict__ cw, const float* __restrict__ mw,
                         __bf16* __restrict__ wk3, __bf16* __restrict__ mlpB,
                         __bf16* __restrict__ zp) {
  int i = blockIdx.x * 256 + threadIdx.x;
  if (i < 3 * C_DIM * C_DIM) {
    int o = i / 768;
    int rem = i - o * 768;
    int tap = rem >> 8;
    int ii = rem & 255;
    wk3[i] = bfbits(f2bf_rn(cw[(size_t)o * 768 + ii * 3 + tap]));
  } else {
    int m = i - 3 * C_DIM * C_DIM;
    if (m < 512 * 256) {
      int r = m >> 8;
      int col = m & 255;
      mlpB[m] = bfbits(f2bf_rn(mw[(size_t)(r & 255) * 512 + ((r >> 8) << 8) + col]));
    }
  }
  if (blockIdx.x == 0 && threadIdx.x < 128) zp[threadIdx.x] = bfbits(0);
}

extern "C" void kernel_launch(void* const* d_in, const int* in_sizes, int n_in,
                              void* d_out, int out_size, void* d_ws, size_t ws_size,
                              hipStream_t stream) {
  const float* x = (const float*)d_in[0];
  const float* conv_w = (const float*)d_in[2];
  const float* conv_b = (const float*)d_in[3];
  const float* mlp_w = (const float*)d_in[4];
  const float* mlp_b = (const float*)d_in[5];
  float* out = (float*)d_out;

  char* ws = (char*)d_ws;
  size_t off = 0;
  auto alloc = [&](size_t bytes) -> void* {
    void* p = ws + off;
    off += (bytes + 255) & ~(size_t)255;
    return p;
  };
  float* gram = (float*)alloc((size_t)BS * T_DIM * T_DIM * 4);
  __bf16* Fh = (__bf16*)alloc((size_t)NPTS * C_DIM * 2);
  __bf16* Fl = (__bf16*)alloc((size_t)NPTS * C_DIM * 2);
  float* convout = (float*)alloc((size_t)NPTS * C_DIM * 4);
  float* mlpout = (float*)alloc((size_t)NPTS * 512 * 4);
  float* sq = (float*)alloc((size_t)NPTS * 4);
  int* idxb = (int*)alloc((size_t)NPTS * KNB * 4);
  float* wb = (float*)alloc((size_t)NPTS * KNB * 4);
  __bf16* wk3 = (__bf16*)alloc((size_t)3 * C_DIM * C_DIM * 2);
  __bf16* mlpB = (__bf16*)alloc((size_t)512 * 256 * 2);
  __bf16* zp = (__bf16*)alloc(512);

  k_repack<<<dim3(1280), 256, 0, stream>>>(conv_w, mlp_w, wk3, mlpB, zp);
  k_transpose_split<<<dim3(T_DIM / 32, C_DIM / 32, BS), 256, 0, stream>>>(x, Fh, Fl);
  k_sq<<<dim3(NPTS / 4), 256, 0, stream>>>(Fh, Fl, sq);

  k_gram_sym<<<dim3(136, BS), 256, 0, stream>>>(Fh, Fl, gram);
  k_topk<<<dim3(T_DIM / 4, BS), 256, 0, stream>>>(gram, sq, idxb, wb);

  k_gemm16<<<dim3(512 / 128, NPTS / 128), 256, 0, stream>>>(Fh, mlpB, mlpout, 512, 256, 0, zp);
  k_gemm16<<<dim3(256 / 128, NPTS / 128), 256, 0, stream>>>(Fh, wk3, convout, 256, 768, 1, zp);

  k_gfinal<<<dim3((T_DIM / 2) / 32, C_DIM / 32, BS), 256, 0, stream>>>(
      mlpout, mlp_b, idxb, wb, convout, conv_b, out);
}

// Round 7
// 196.494 us; speedup vs baseline: 1.1348x; 1.1348x over previous
//
#include <hip/hip_runtime.h>
#include <hip/hip_bf16.h>
#include <cstdint>

#define T_DIM 2048
#define C_DIM 256
#define BS 8
#define NPTS (BS * T_DIM)
#define KNB 10

typedef __bf16 bf16x8 __attribute__((ext_vector_type(8)));
typedef float f32x4 __attribute__((ext_vector_type(4)));

#define AS1 __attribute__((address_space(1)))
#define AS3 __attribute__((address_space(3)))

__device__ __forceinline__ unsigned short f2bf_rn(float f) {
  unsigned u = __float_as_uint(f);
  unsigned r = (u + 0x7FFFu + ((u >> 16) & 1u)) >> 16;
  return (unsigned short)r;
}
__device__ __forceinline__ float bfbits2f(unsigned short h) {
  return __uint_as_float((unsigned)h << 16);
}
__device__ __forceinline__ __bf16 bfbits(unsigned short h) {
  return __builtin_bit_cast(__bf16, h);
}

// pinned dif computation: identical instruction sequence at every use site so
// hot-kernel keys, theta, count keys, and fix-kernel keys are bit-identical.
__device__ __forceinline__ unsigned key_hi(float sqi, float sqj, float gv) {
  float dif = __fmaf_rn(-2.0f, gv, __fadd_rn(sqi, sqj));
  unsigned u = __float_as_uint(dif);
  return (u & 0x80000000u) ? ~u : (u | 0x80000000u);
}

// ---- stage a 128x64 bf16 tile into XOR-swizzled LDS via global_load_lds ----
__device__ __forceinline__ void stage_tile(const __bf16* __restrict__ src, size_t row0,
                                           int ld, int k0, __bf16* lds, int w, int l) {
  int kofs = ((l & 7) ^ (l >> 3)) * 8;
  const __bf16* g0 = src + (row0 + (size_t)(l >> 3)) * ld + k0 + kofs;
  __bf16* lbase = lds + (size_t)(w * 4) * 512;
#pragma unroll
  for (int q4 = 0; q4 < 4; ++q4) {
    __builtin_amdgcn_global_load_lds((AS1 void*)(g0 + (size_t)(w * 4 + q4) * 8 * ld),
                                     (AS3 void*)(lbase + q4 * 512), 16, 0, 0);
  }
}

// conv im2col staging: K=768 = 3 taps x 256
__device__ __forceinline__ void stage_tile_conv(const __bf16* __restrict__ src, int m0,
                                                int k0in, const __bf16* __restrict__ zp,
                                                __bf16* lds, int w, int l) {
  int tap = k0in >> 8;
  int kshift = tap - 1;
  int k0 = k0in & 255;
  int kofs = ((l & 7) ^ (l >> 3)) * 8;
  int mb = m0 & (T_DIM - 1);
#pragma unroll
  for (int q4 = 0; q4 < 4; ++q4) {
    int q = w * 4 + q4;
    int row = q * 8 + (l >> 3);
    int t = mb + row + kshift;
    const __bf16* g = ((unsigned)t < (unsigned)T_DIM)
                          ? (src + (size_t)(m0 + row + kshift) * C_DIM + k0 + kofs)
                          : (zp + kofs);
    __builtin_amdgcn_global_load_lds((AS1 void*)g, (AS3 void*)(lds + q * 512), 16, 0, 0);
  }
}

__device__ __forceinline__ bf16x8 read_frag(const __bf16* lds, int t16, int ks, int l) {
  int row = t16 * 16 + (l & 15);
  int kb = ks * 64 + ((l >> 4) << 4);
  int byte = row * 128 + (kb ^ ((row & 7) << 4));
  return *(const bf16x8*)((const char*)lds + byte);
}

// ---------------- transpose + hi/lo bf16 split ----------------
__global__ __launch_bounds__(256) void k_transpose_split(const float* __restrict__ x,
                                                         __bf16* __restrict__ Fh,
                                                         __bf16* __restrict__ Fl) {
  __shared__ float tile[32][33];
  int b = blockIdx.z;
  int t0 = blockIdx.x * 32;
  int c0 = blockIdx.y * 32;
  int tx = threadIdx.x & 31, ty = threadIdx.x >> 5;
  const float* xb = x + (size_t)b * C_DIM * T_DIM;
#pragma unroll
  for (int r = 0; r < 4; ++r) {
    int c = c0 + ty + 8 * r;
    tile[ty + 8 * r][tx] = xb[(size_t)c * T_DIM + t0 + tx];
  }
  __syncthreads();
#pragma unroll
  for (int r = 0; r < 4; ++r) {
    int t = t0 + ty + 8 * r;
    float v = tile[tx][ty + 8 * r];
    unsigned short hb = f2bf_rn(v);
    float lo = v - bfbits2f(hb);
    size_t o = ((size_t)b * T_DIM + t) * C_DIM + c0 + tx;
    Fh[o] = bfbits(hb);
    Fl[o] = bfbits(f2bf_rn(lo));
  }
}

// ---------------- sq[n] = sum_c (hi+lo)^2 ----------------
__global__ __launch_bounds__(256) void k_sq(const __bf16* __restrict__ Fh,
                                            const __bf16* __restrict__ Fl,
                                            float* __restrict__ sq) {
  int n = blockIdx.x * 4 + (threadIdx.x >> 6);
  int lane = threadIdx.x & 63;
  ushort4 hv = ((const ushort4*)Fh)[(size_t)n * 64 + lane];
  ushort4 lv = ((const ushort4*)Fl)[(size_t)n * 64 + lane];
  float s = 0.f;
  {
    float v;
    v = bfbits2f(hv.x) + bfbits2f(lv.x); s = fmaf(v, v, s);
    v = bfbits2f(hv.y) + bfbits2f(lv.y); s = fmaf(v, v, s);
    v = bfbits2f(hv.z) + bfbits2f(lv.z); s = fmaf(v, v, s);
    v = bfbits2f(hv.w) + bfbits2f(lv.w); s = fmaf(v, v, s);
  }
#pragma unroll
  for (int d = 1; d < 64; d <<= 1) s += __shfl_xor(s, d, 64);
  if (lane == 0) sq[n] = s;
}

// ---------------- Gram via split-bf16 MFMA, symmetric ----------------
__global__ __launch_bounds__(256, 2) void k_gram_sym(const __bf16* __restrict__ Fh,
                                                     const __bf16* __restrict__ Fl,
                                                     float* __restrict__ gram) {
  __shared__ __align__(16) char smem[65536];
  __bf16* Ah = (__bf16*)smem;
  __bf16* Al = (__bf16*)(smem + 16384);
  __bf16* Bh = (__bf16*)(smem + 32768);
  __bf16* Bl = (__bf16*)(smem + 49152);

  int b = blockIdx.y;
  int ti = blockIdx.x;
  int by = (int)((sqrtf(8.0f * (float)ti + 1.0f) - 1.0f) * 0.5f);
  if ((by + 1) * (by + 2) / 2 <= ti) by++;
  int bx = ti - by * (by + 1) / 2;

  size_t base = (size_t)b * T_DIM;
  int m0 = by * 128, n0 = bx * 128;
  int tid = threadIdx.x, w = tid >> 6, l = tid & 63;
  int wr = w >> 1, wc = w & 1;
  f32x4 acc[4][4];
#pragma unroll
  for (int i = 0; i < 4; ++i)
#pragma unroll
    for (int j = 0; j < 4; ++j) acc[i][j] = {0.f, 0.f, 0.f, 0.f};

  for (int k0 = 0; k0 < C_DIM; k0 += 64) {
    stage_tile(Fh, base + m0, C_DIM, k0, Ah, w, l);
    stage_tile(Fl, base + m0, C_DIM, k0, Al, w, l);
    stage_tile(Fh, base + n0, C_DIM, k0, Bh, w, l);
    stage_tile(Fl, base + n0, C_DIM, k0, Bl, w, l);
    __syncthreads();
#pragma unroll
    for (int ks = 0; ks < 2; ++ks) {
      bf16x8 ah[4], bh[4], x[4];
#pragma unroll
      for (int i = 0; i < 4; ++i) ah[i] = read_frag(Ah, wr * 4 + i, ks, l);
#pragma unroll
      for (int j = 0; j < 4; ++j) bh[j] = read_frag(Bh, wc * 4 + j, ks, l);
#pragma unroll
      for (int i = 0; i < 4; ++i)
#pragma unroll
        for (int j = 0; j < 4; ++j)
          acc[i][j] = __builtin_amdgcn_mfma_f32_16x16x32_bf16(ah[i], bh[j], acc[i][j], 0, 0, 0);
#pragma unroll
      for (int i = 0; i < 4; ++i) x[i] = read_frag(Al, wr * 4 + i, ks, l);
#pragma unroll
      for (int i = 0; i < 4; ++i)
#pragma unroll
        for (int j = 0; j < 4; ++j)
          acc[i][j] = __builtin_amdgcn_mfma_f32_16x16x32_bf16(x[i], bh[j], acc[i][j], 0, 0, 0);
#pragma unroll
      for (int j = 0; j < 4; ++j) x[j] = read_frag(Bl, wc * 4 + j, ks, l);
#pragma unroll
      for (int i = 0; i < 4; ++i)
#pragma unroll
        for (int j = 0; j < 4; ++j)
          acc[i][j] = __builtin_amdgcn_mfma_f32_16x16x32_bf16(ah[i], x[j], acc[i][j], 0, 0, 0);
    }
    __syncthreads();
  }

  float* gout = gram + (size_t)b * T_DIM * T_DIM;
#pragma unroll
  for (int i = 0; i < 4; ++i) {
    int mrow = m0 + wr * 64 + i * 16 + ((l >> 4) << 2);
#pragma unroll
    for (int j = 0; j < 4; ++j) {
      int ncol = n0 + wc * 64 + j * 16 + (l & 15);
      float* cp = gout + (size_t)mrow * T_DIM + ncol;
#pragma unroll
      for (int r = 0; r < 4; ++r) cp[(size_t)r * T_DIM] = acc[i][j][r];
    }
  }

  if (bx != by) {
    float* Tbuf = (float*)smem;
#pragma unroll
    for (int h = 0; h < 2; ++h) {
      __syncthreads();
      if (wc == h) {
#pragma unroll
        for (int j = 0; j < 4; ++j) {
          int cH = j * 16 + (l & 15);
          float* dst = Tbuf + cH * 132 + wr * 64 + ((l >> 4) << 2);
#pragma unroll
          for (int i = 0; i < 4; ++i) *(f32x4*)(dst + i * 16) = acc[i][j];
        }
      }
      __syncthreads();
      int cH = tid >> 5;
      int c4 = (tid & 31) * 4;
#pragma unroll
      for (int p = 0; p < 8; ++p) {
        f32x4 v = *(const f32x4*)(Tbuf + (size_t)(p * 8 + cH) * 132 + c4);
        *(f32x4*)(gout + (size_t)(n0 + h * 64 + p * 8 + cH) * T_DIM + m0 + c4) = v;
      }
    }
  }
}

// ---------------- plain bf16 GEMM C = A.B^T ----------------
__global__ __launch_bounds__(256, 2) void k_gemm16(const __bf16* __restrict__ A,
                                                   const __bf16* __restrict__ Bm,
                                                   float* __restrict__ C, int N, int K,
                                                   int conv, const __bf16* __restrict__ zp) {
  __shared__ __bf16 As[128 * 64], Bs[128 * 64];
  int m0 = blockIdx.y * 128, n0 = blockIdx.x * 128;
  int tid = threadIdx.x, w = tid >> 6, l = tid & 63;
  int wr = w >> 1, wc = w & 1;
  f32x4 acc[4][4];
#pragma unroll
  for (int i = 0; i < 4; ++i)
#pragma unroll
    for (int j = 0; j < 4; ++j) acc[i][j] = {0.f, 0.f, 0.f, 0.f};

  for (int k0 = 0; k0 < K; k0 += 64) {
    if (conv)
      stage_tile_conv(A, m0, k0, zp, As, w, l);
    else
      stage_tile(A, (size_t)m0, C_DIM, k0, As, w, l);
    stage_tile(Bm, (size_t)n0, K, k0, Bs, w, l);
    __syncthreads();
#pragma unroll
    for (int ks = 0; ks < 2; ++ks) {
      bf16x8 af[4], bf_[4];
#pragma unroll
      for (int i = 0; i < 4; ++i) af[i] = read_frag(As, wr * 4 + i, ks, l);
#pragma unroll
      for (int j = 0; j < 4; ++j) bf_[j] = read_frag(Bs, wc * 4 + j, ks, l);
#pragma unroll
      for (int i = 0; i < 4; ++i)
#pragma unroll
        for (int j = 0; j < 4; ++j)
          acc[i][j] = __builtin_amdgcn_mfma_f32_16x16x32_bf16(af[i], bf_[j], acc[i][j], 0, 0, 0);
    }
    __syncthreads();
  }
#pragma unroll
  for (int i = 0; i < 4; ++i) {
    int mrow = m0 + wr * 64 + i * 16 + ((l >> 4) << 2);
#pragma unroll
    for (int j = 0; j < 4; ++j) {
      int ncol = n0 + wc * 64 + j * 16 + (l & 15);
      float* cp = C + (size_t)mrow * N + ncol;
#pragma unroll
      for (int r = 0; r < 4; ++r) cp[(size_t)r * N] = acc[i][j][r];
    }
  }
}

// ---------------- per-row top-10 HOT kernel: float4 min-2 filter + count; flag on miss ----
// Key semantics identical to R3-R6: u64 key = (flip32(dif) << 32) | j, dif pinned via
// key_hi(). 4 min-2 trackers mapped to float4 components (exact merge). Fast path
// provably exact when count(full row key < theta) == 9; otherwise flag row for fix.
__global__ __launch_bounds__(256) void k_topk(const float* __restrict__ gram,
                                              const float* __restrict__ sq,
                                              int* __restrict__ idxo,
                                              float* __restrict__ wo,
                                              int* __restrict__ flags) {
  int lb = blockIdx.y;
  const float* gramb = gram + (size_t)lb * T_DIM * T_DIM;
  const float* sqb = sq + (size_t)lb * T_DIM;
  int* idxb = idxo + (size_t)lb * T_DIM * KNB;
  float* wbp = wo + (size_t)lb * T_DIM * KNB;

  int row = blockIdx.x * 4 + (threadIdx.x >> 6);
  int lane = threadIdx.x & 63;
  float sqi = sqb[row];
  const float* g = gramb + (size_t)row * T_DIM;
  const f32x4* g4 = (const f32x4*)g;
  const f32x4* s4 = (const f32x4*)sqb;

  // Phase 1: 4 min-2 trackers, one per float4 component (pure ILP, no stash)
  unsigned long long p0[4], p1[4];
#pragma unroll
  for (int q = 0; q < 4; ++q) { p0[q] = ~0ull; p1[q] = ~0ull; }
#pragma unroll 4
  for (int tq = 0; tq < 8; ++tq) {
    int i4 = lane + 64 * tq;
    f32x4 gv = g4[i4];
    f32x4 sv = s4[i4];
    unsigned bj = (unsigned)(i4 * 4);
#pragma unroll
    for (int e = 0; e < 4; ++e) {
      unsigned u = key_hi(sqi, sv[e], gv[e]);
      unsigned long long key = ((unsigned long long)u << 32) | (bj + e);
      unsigned long long mx = (key > p0[e]) ? key : p0[e];
      p0[e] = (key < p0[e]) ? key : p0[e];
      p1[e] = (mx < p1[e]) ? mx : p1[e];
    }
  }
  // exact merge of 4 min-2 pairs -> per-lane min-2 (m0, m1)
  unsigned long long m0 = p0[0], m1 = p1[0];
#pragma unroll
  for (int q = 1; q < 4; ++q) {
    unsigned long long k0 = p0[q], k1 = p1[q];
    unsigned long long mx = (k0 > m0) ? k0 : m0;
    m0 = (k0 < m0) ? k0 : m0;
    m1 = (mx < m1) ? mx : m1;
    m1 = (k1 < m1) ? k1 : m1;  // k1 >= k0 >= new m0: only second slot possible
  }

  // Phase 2: 10-round wave extract-min over the 128 candidates; write results
  unsigned long long theta = 0;
#pragma unroll
  for (int s = 0; s < KNB; ++s) {
    unsigned long long m = m0;
#pragma unroll
    for (int d = 1; d < 64; d <<= 1) {
      unsigned long long o = __shfl_xor(m, d, 64);
      m = (o < m) ? o : m;
    }
    unsigned long long bal = __ballot(m0 == m);
    int leader = (int)__builtin_ctzll(bal);
    if (lane == leader) { m0 = m1; m1 = ~0ull; }
    if (lane == 0) {
      int j = (int)(unsigned)(m & 0xffffffffull);
      unsigned su = (unsigned)(m >> 32);
      unsigned bits = (su & 0x80000000u) ? (su & 0x7fffffffu) : ~su;
      float dif = __uint_as_float(bits);
      float sqj = sqb[j];
      float num = 0.5f * (sqi + sqj - dif);
      float wv = num / (sqrtf(sqi) * sqrtf(sqj));
      idxb[row * KNB + s] = j;
      wbp[row * KNB + s] = wv;
    }
    theta = m;
  }

  // Phase 3: exact strict-order count vs theta (float4 re-read, L2-hot)
  unsigned thi = (unsigned)(theta >> 32);
  unsigned tlo = (unsigned)(theta & 0xffffffffull);
  int c = 0;
#pragma unroll 4
  for (int tq = 0; tq < 8; ++tq) {
    int i4 = lane + 64 * tq;
    f32x4 gv = g4[i4];
    f32x4 sv = s4[i4];
    unsigned bj = (unsigned)(i4 * 4);
#pragma unroll
    for (int e = 0; e < 4; ++e) {
      unsigned u = key_hi(sqi, sv[e], gv[e]);
      unsigned j = bj + e;
      c += (u < thi) || ((u == thi) && (j < tlo));
    }
  }
#pragma unroll
  for (int d = 1; d < 64; d <<= 1) c += __shfl_xor(c, d, 64);

  if (c != 9 && lane == 0) flags[(size_t)lb * T_DIM + row] = 1;
}

// ---------------- FIX kernel: flagged rows only (rare), full sorted-10 insert ----------------
__global__ __launch_bounds__(256) void k_topk_fix(const float* __restrict__ gram,
                                                  const float* __restrict__ sq,
                                                  const int* __restrict__ flags,
                                                  int* __restrict__ idxo,
                                                  float* __restrict__ wo) {
  int lb = blockIdx.y;
  int row = blockIdx.x * 4 + (threadIdx.x >> 6);
  if (!flags[(size_t)lb * T_DIM + row]) return;  // wave-uniform
  const float* gramb = gram + (size_t)lb * T_DIM * T_DIM;
  const float* sqb = sq + (size_t)lb * T_DIM;
  int* idxb = idxo + (size_t)lb * T_DIM * KNB;
  float* wbp = wo + (size_t)lb * T_DIM * KNB;
  int lane = threadIdx.x & 63;
  float sqi = sqb[row];
  const float* g = gramb + (size_t)row * T_DIM;

  unsigned long long b0 = ~0ull, b1 = ~0ull, b2 = ~0ull, b3 = ~0ull, b4 = ~0ull,
                     b5 = ~0ull, b6 = ~0ull, b7 = ~0ull, b8 = ~0ull, b9 = ~0ull;
  for (int t = 0; t < 32; ++t) {
    unsigned j = (unsigned)(lane + 64 * t);
    unsigned u = key_hi(sqi, sqb[j], g[j]);
    unsigned long long key = ((unsigned long long)u << 32) | j;
    if (key < b9) {
      b9 = key;
      unsigned long long tt;
      if (b9 < b8) { tt = b8; b8 = b9; b9 = tt; }
      if (b8 < b7) { tt = b7; b7 = b8; b8 = tt; }
      if (b7 < b6) { tt = b6; b6 = b7; b7 = tt; }
      if (b6 < b5) { tt = b5; b5 = b6; b6 = tt; }
      if (b5 < b4) { tt = b4; b4 = b5; b5 = tt; }
      if (b4 < b3) { tt = b3; b3 = b4; b4 = tt; }
      if (b3 < b2) { tt = b2; b2 = b3; b3 = tt; }
      if (b2 < b1) { tt = b1; b1 = b2; b2 = tt; }
      if (b1 < b0) { tt = b0; b0 = b1; b1 = tt; }
    }
  }
#pragma unroll
  for (int s = 0; s < KNB; ++s) {
    unsigned long long m = b0;
#pragma unroll
    for (int d = 1; d < 64; d <<= 1) {
      unsigned long long o = __shfl_xor(m, d, 64);
      m = (o < m) ? o : m;
    }
    unsigned long long bal = __ballot(b0 == m);
    int leader = (int)__builtin_ctzll(bal);
    if (lane == leader) {
      b0 = b1; b1 = b2; b2 = b3; b3 = b4; b4 = b5;
      b5 = b6; b6 = b7; b7 = b8; b8 = b9; b9 = ~0ull;
    }
    if (lane == 0) {
      int j = (int)(unsigned)(m & 0xffffffffull);
      unsigned su = (unsigned)(m >> 32);
      unsigned bits = (su & 0x80000000u) ? (su & 0x7fffffffu) : ~su;
      float dif = __uint_as_float(bits);
      float sqj = sqb[j];
      float num = 0.5f * (sqi + sqj - dif);
      float wv = num / (sqrtf(sqi) * sqrtf(sqj));
      idxb[row * KNB + s] = j;
      wbp[row * KNB + s] = wv;
    }
  }
}

// ---------------- fused gmax + conv-bias + relu + pairwise maxpool + transpose ----------------
__global__ __launch_bounds__(256) void k_gfinal(const float* __restrict__ mlpout,
                                                const float* __restrict__ mlp_b,
                                                const int* __restrict__ idxo,
                                                const float* __restrict__ wo,
                                                const float* __restrict__ convb,
                                                const float* __restrict__ cb,
                                                float* __restrict__ out) {
  __shared__ float tile[32][33];
  __shared__ int sj[64][KNB];
  __shared__ float sw[64][KNB];
  int b = blockIdx.z, c0 = blockIdx.y * 32, t20 = blockIdx.x * 32;
  int tid = threadIdx.x;
  int nbase = b * T_DIM + t20 * 2;
  for (int e = tid; e < 64 * KNB; e += 256) {
    int ln = e / KNB, k = e - ln * KNB;
    sj[ln][k] = b * T_DIM + idxo[(size_t)(nbase + ln) * KNB + k];
    sw[ln][k] = wo[(size_t)(nbase + ln) * KNB + k];
  }
  __syncthreads();
  int tx = tid & 31, ty = tid >> 5;
  int c = c0 + tx;
  float bias_c = cb[c];
  float mbias = mlp_b[c];
#pragma unroll
  for (int rr = 0; rr < 4; ++rr) {
    int lt2 = ty + 8 * rr;
    float res[2];
#pragma unroll
    for (int s = 0; s < 2; ++s) {
      int ln = 2 * lt2 + s;
      int n = nbase + ln;
      float q = mlpout[(size_t)n * 512 + 256 + c] + mbias;
      float mx = -3.4e38f;
#pragma unroll
      for (int k = 0; k < KNB; ++k) {
        float v = (mlpout[(size_t)sj[ln][k] * 512 + c] + q) * sw[ln][k];
        mx = fmaxf(mx, v);
      }
      float v = convb[(size_t)n * C_DIM + c] + mx + bias_c;
      res[s] = fmaxf(v, 0.f);
    }
    tile[lt2][tx] = fmaxf(res[0], res[1]);
  }
  __syncthreads();
#pragma unroll
  for (int rr = 0; rr < 4; ++rr) {
    int cc = c0 + ty + 8 * rr;
    out[((size_t)b * C_DIM + cc) * (T_DIM / 2) + t20 + tx] = tile[tx][ty + 8 * rr];
  }
}

// ---------------- merged repack + flags zeroing ----------------
__global__ void k_repack(const float* __restrict__ cw, const float* __restrict__ mw,
                         __bf16* __restrict__ wk3, __bf16* __restrict__ mlpB,
                         __bf16* __restrict__ zp, int* __restrict__ flags) {
  int i = blockIdx.x * 256 + threadIdx.x;
  if (i < NPTS) flags[i] = 0;
  if (i < 3 * C_DIM * C_DIM) {
    int o = i / 768;
    int rem = i - o * 768;
    int tap = rem >> 8;
    int ii = rem & 255;
    wk3[i] = bfbits(f2bf_rn(cw[(size_t)o * 768 + ii * 3 + tap]));
  } else {
    int m = i - 3 * C_DIM * C_DIM;
    if (m < 512 * 256) {
      int r = m >> 8;
      int col = m & 255;
      mlpB[m] = bfbits(f2bf_rn(mw[(size_t)(r & 255) * 512 + ((r >> 8) << 8) + col]));
    }
  }
  if (blockIdx.x == 0 && threadIdx.x < 128) zp[threadIdx.x] = bfbits(0);
}

extern "C" void kernel_launch(void* const* d_in, const int* in_sizes, int n_in,
                              void* d_out, int out_size, void* d_ws, size_t ws_size,
                              hipStream_t stream) {
  const float* x = (const float*)d_in[0];
  const float* conv_w = (const float*)d_in[2];
  const float* conv_b = (const float*)d_in[3];
  const float* mlp_w = (const float*)d_in[4];
  const float* mlp_b = (const float*)d_in[5];
  float* out = (float*)d_out;

  char* ws = (char*)d_ws;
  size_t off = 0;
  auto alloc = [&](size_t bytes) -> void* {
    void* p = ws + off;
    off += (bytes + 255) & ~(size_t)255;
    return p;
  };
  float* gram = (float*)alloc((size_t)BS * T_DIM * T_DIM * 4);
  __bf16* Fh = (__bf16*)alloc((size_t)NPTS * C_DIM * 2);
  __bf16* Fl = (__bf16*)alloc((size_t)NPTS * C_DIM * 2);
  float* convout = (float*)alloc((size_t)NPTS * C_DIM * 4);
  float* mlpout = (float*)alloc((size_t)NPTS * 512 * 4);
  float* sq = (float*)alloc((size_t)NPTS * 4);
  int* idxb = (int*)alloc((size_t)NPTS * KNB * 4);
  float* wb = (float*)alloc((size_t)NPTS * KNB * 4);
  int* flags = (int*)alloc((size_t)NPTS * 4);
  __bf16* wk3 = (__bf16*)alloc((size_t)3 * C_DIM * C_DIM * 2);
  __bf16* mlpB = (__bf16*)alloc((size_t)512 * 256 * 2);
  __bf16* zp = (__bf16*)alloc(512);

  k_repack<<<dim3(1280), 256, 0, stream>>>(conv_w, mlp_w, wk3, mlpB, zp, flags);
  k_transpose_split<<<dim3(T_DIM / 32, C_DIM / 32, BS), 256, 0, stream>>>(x, Fh, Fl);
  k_sq<<<dim3(NPTS / 4), 256, 0, stream>>>(Fh, Fl, sq);

  k_gram_sym<<<dim3(136, BS), 256, 0, stream>>>(Fh, Fl, gram);
  k_topk<<<dim3(T_DIM / 4, BS), 256, 0, stream>>>(gram, sq, idxb, wb, flags);
  k_topk_fix<<<dim3(T_DIM / 4, BS), 256, 0, stream>>>(gram, sq, flags, idxb, wb);

  k_gemm16<<<dim3(512 / 128, NPTS / 128), 256, 0, stream>>>(Fh, mlpB, mlpout, 512, 256, 0, zp);
  k_gemm16<<<dim3(256 / 128, NPTS / 128), 256, 0, stream>>>(Fh, wk3, convout, 256, 768, 1, zp);

  k_gfinal<<<dim3((T_DIM / 2) / 32, C_DIM / 32, BS), 256, 0, stream>>>(
      mlpout, mlp_b, idxb, wb, convout, conv_b, out);
}

// Round 8
// 187.470 us; speedup vs baseline: 1.1894x; 1.0481x over previous
//
#include <hip/hip_runtime.h>
#include <hip/hip_bf16.h>
#include <cstdint>

#define T_DIM 2048
#define C_DIM 256
#define BS 8
#define NPTS (BS * T_DIM)
#define KNB 10

typedef __bf16 bf16x8 __attribute__((ext_vector_type(8)));
typedef float f32x4 __attribute__((ext_vector_type(4)));

#define AS1 __attribute__((address_space(1)))
#define AS3 __attribute__((address_space(3)))

__device__ __forceinline__ unsigned short f2bf_rn(float f) {
  unsigned u = __float_as_uint(f);
  unsigned r = (u + 0x7FFFu + ((u >> 16) & 1u)) >> 16;
  return (unsigned short)r;
}
__device__ __forceinline__ float bfbits2f(unsigned short h) {
  return __uint_as_float((unsigned)h << 16);
}
__device__ __forceinline__ __bf16 bfbits(unsigned short h) {
  return __builtin_bit_cast(__bf16, h);
}

// pinned dif computation: identical instruction sequence at every use site so
// hot-kernel keys, theta, and fix-kernel keys are bit-identical.
__device__ __forceinline__ unsigned key_hi(float sqi, float sqj, float gv) {
  float dif = __fmaf_rn(-2.0f, gv, __fadd_rn(sqi, sqj));
  unsigned u = __float_as_uint(dif);
  return (u & 0x80000000u) ? ~u : (u | 0x80000000u);
}

// ---- stage a 128x64 bf16 tile into XOR-swizzled LDS via global_load_lds ----
__device__ __forceinline__ void stage_tile(const __bf16* __restrict__ src, size_t row0,
                                           int ld, int k0, __bf16* lds, int w, int l) {
  int kofs = ((l & 7) ^ (l >> 3)) * 8;
  const __bf16* g0 = src + (row0 + (size_t)(l >> 3)) * ld + k0 + kofs;
  __bf16* lbase = lds + (size_t)(w * 4) * 512;
#pragma unroll
  for (int q4 = 0; q4 < 4; ++q4) {
    __builtin_amdgcn_global_load_lds((AS1 void*)(g0 + (size_t)(w * 4 + q4) * 8 * ld),
                                     (AS3 void*)(lbase + q4 * 512), 16, 0, 0);
  }
}

// conv im2col staging: K=768 = 3 taps x 256
__device__ __forceinline__ void stage_tile_conv(const __bf16* __restrict__ src, int m0,
                                                int k0in, const __bf16* __restrict__ zp,
                                                __bf16* lds, int w, int l) {
  int tap = k0in >> 8;
  int kshift = tap - 1;
  int k0 = k0in & 255;
  int kofs = ((l & 7) ^ (l >> 3)) * 8;
  int mb = m0 & (T_DIM - 1);
#pragma unroll
  for (int q4 = 0; q4 < 4; ++q4) {
    int q = w * 4 + q4;
    int row = q * 8 + (l >> 3);
    int t = mb + row + kshift;
    const __bf16* g = ((unsigned)t < (unsigned)T_DIM)
                          ? (src + (size_t)(m0 + row + kshift) * C_DIM + k0 + kofs)
                          : (zp + kofs);
    __builtin_amdgcn_global_load_lds((AS1 void*)g, (AS3 void*)(lds + q * 512), 16, 0, 0);
  }
}

__device__ __forceinline__ bf16x8 read_frag(const __bf16* lds, int t16, int ks, int l) {
  int row = t16 * 16 + (l & 15);
  int kb = ks * 64 + ((l >> 4) << 4);
  int byte = row * 128 + (kb ^ ((row & 7) << 4));
  return *(const bf16x8*)((const char*)lds + byte);
}

// ---------------- transpose + hi/lo bf16 split ----------------
__global__ __launch_bounds__(256) void k_transpose_split(const float* __restrict__ x,
                                                         __bf16* __restrict__ Fh,
                                                         __bf16* __restrict__ Fl) {
  __shared__ float tile[32][33];
  int b = blockIdx.z;
  int t0 = blockIdx.x * 32;
  int c0 = blockIdx.y * 32;
  int tx = threadIdx.x & 31, ty = threadIdx.x >> 5;
  const float* xb = x + (size_t)b * C_DIM * T_DIM;
#pragma unroll
  for (int r = 0; r < 4; ++r) {
    int c = c0 + ty + 8 * r;
    tile[ty + 8 * r][tx] = xb[(size_t)c * T_DIM + t0 + tx];
  }
  __syncthreads();
#pragma unroll
  for (int r = 0; r < 4; ++r) {
    int t = t0 + ty + 8 * r;
    float v = tile[tx][ty + 8 * r];
    unsigned short hb = f2bf_rn(v);
    float lo = v - bfbits2f(hb);
    size_t o = ((size_t)b * T_DIM + t) * C_DIM + c0 + tx;
    Fh[o] = bfbits(hb);
    Fl[o] = bfbits(f2bf_rn(lo));
  }
}

// ---------------- sq[n] = sum_c (hi+lo)^2 ----------------
__global__ __launch_bounds__(256) void k_sq(const __bf16* __restrict__ Fh,
                                            const __bf16* __restrict__ Fl,
                                            float* __restrict__ sq) {
  int n = blockIdx.x * 4 + (threadIdx.x >> 6);
  int lane = threadIdx.x & 63;
  ushort4 hv = ((const ushort4*)Fh)[(size_t)n * 64 + lane];
  ushort4 lv = ((const ushort4*)Fl)[(size_t)n * 64 + lane];
  float s = 0.f;
  {
    float v;
    v = bfbits2f(hv.x) + bfbits2f(lv.x); s = fmaf(v, v, s);
    v = bfbits2f(hv.y) + bfbits2f(lv.y); s = fmaf(v, v, s);
    v = bfbits2f(hv.z) + bfbits2f(lv.z); s = fmaf(v, v, s);
    v = bfbits2f(hv.w) + bfbits2f(lv.w); s = fmaf(v, v, s);
  }
#pragma unroll
  for (int d = 1; d < 64; d <<= 1) s += __shfl_xor(s, d, 64);
  if (lane == 0) sq[n] = s;
}

// ---------------- Gram via split-bf16 MFMA, symmetric ----------------
__global__ __launch_bounds__(256, 2) void k_gram_sym(const __bf16* __restrict__ Fh,
                                                     const __bf16* __restrict__ Fl,
                                                     float* __restrict__ gram) {
  __shared__ __align__(16) char smem[65536];
  __bf16* Ah = (__bf16*)smem;
  __bf16* Al = (__bf16*)(smem + 16384);
  __bf16* Bh = (__bf16*)(smem + 32768);
  __bf16* Bl = (__bf16*)(smem + 49152);

  int b = blockIdx.y;
  int ti = blockIdx.x;
  int by = (int)((sqrtf(8.0f * (float)ti + 1.0f) - 1.0f) * 0.5f);
  if ((by + 1) * (by + 2) / 2 <= ti) by++;
  int bx = ti - by * (by + 1) / 2;

  size_t base = (size_t)b * T_DIM;
  int m0 = by * 128, n0 = bx * 128;
  int tid = threadIdx.x, w = tid >> 6, l = tid & 63;
  int wr = w >> 1, wc = w & 1;
  f32x4 acc[4][4];
#pragma unroll
  for (int i = 0; i < 4; ++i)
#pragma unroll
    for (int j = 0; j < 4; ++j) acc[i][j] = {0.f, 0.f, 0.f, 0.f};

  for (int k0 = 0; k0 < C_DIM; k0 += 64) {
    stage_tile(Fh, base + m0, C_DIM, k0, Ah, w, l);
    stage_tile(Fl, base + m0, C_DIM, k0, Al, w, l);
    stage_tile(Fh, base + n0, C_DIM, k0, Bh, w, l);
    stage_tile(Fl, base + n0, C_DIM, k0, Bl, w, l);
    __syncthreads();
#pragma unroll
    for (int ks = 0; ks < 2; ++ks) {
      bf16x8 ah[4], bh[4], x[4];
#pragma unroll
      for (int i = 0; i < 4; ++i) ah[i] = read_frag(Ah, wr * 4 + i, ks, l);
#pragma unroll
      for (int j = 0; j < 4; ++j) bh[j] = read_frag(Bh, wc * 4 + j, ks, l);
#pragma unroll
      for (int i = 0; i < 4; ++i)
#pragma unroll
        for (int j = 0; j < 4; ++j)
          acc[i][j] = __builtin_amdgcn_mfma_f32_16x16x32_bf16(ah[i], bh[j], acc[i][j], 0, 0, 0);
#pragma unroll
      for (int i = 0; i < 4; ++i) x[i] = read_frag(Al, wr * 4 + i, ks, l);
#pragma unroll
      for (int i = 0; i < 4; ++i)
#pragma unroll
        for (int j = 0; j < 4; ++j)
          acc[i][j] = __builtin_amdgcn_mfma_f32_16x16x32_bf16(x[i], bh[j], acc[i][j], 0, 0, 0);
#pragma unroll
      for (int j = 0; j < 4; ++j) x[j] = read_frag(Bl, wc * 4 + j, ks, l);
#pragma unroll
      for (int i = 0; i < 4; ++i)
#pragma unroll
        for (int j = 0; j < 4; ++j)
          acc[i][j] = __builtin_amdgcn_mfma_f32_16x16x32_bf16(ah[i], x[j], acc[i][j], 0, 0, 0);
    }
    __syncthreads();
  }

  float* gout = gram + (size_t)b * T_DIM * T_DIM;
#pragma unroll
  for (int i = 0; i < 4; ++i) {
    int mrow = m0 + wr * 64 + i * 16 + ((l >> 4) << 2);
#pragma unroll
    for (int j = 0; j < 4; ++j) {
      int ncol = n0 + wc * 64 + j * 16 + (l & 15);
      float* cp = gout + (size_t)mrow * T_DIM + ncol;
#pragma unroll
      for (int r = 0; r < 4; ++r) cp[(size_t)r * T_DIM] = acc[i][j][r];
    }
  }

  if (bx != by) {
    float* Tbuf = (float*)smem;
#pragma unroll
    for (int h = 0; h < 2; ++h) {
      __syncthreads();
      if (wc == h) {
#pragma unroll
        for (int j = 0; j < 4; ++j) {
          int cH = j * 16 + (l & 15);
          float* dst = Tbuf + cH * 132 + wr * 64 + ((l >> 4) << 2);
#pragma unroll
          for (int i = 0; i < 4; ++i) *(f32x4*)(dst + i * 16) = acc[i][j];
        }
      }
      __syncthreads();
      int cH = tid >> 5;
      int c4 = (tid & 31) * 4;
#pragma unroll
      for (int p = 0; p < 8; ++p) {
        f32x4 v = *(const f32x4*)(Tbuf + (size_t)(p * 8 + cH) * 132 + c4);
        *(f32x4*)(gout + (size_t)(n0 + h * 64 + p * 8 + cH) * T_DIM + m0 + c4) = v;
      }
    }
  }
}

// ---------------- plain bf16 GEMM C = A.B^T ----------------
__global__ __launch_bounds__(256, 2) void k_gemm16(const __bf16* __restrict__ A,
                                                   const __bf16* __restrict__ Bm,
                                                   float* __restrict__ C, int N, int K,
                                                   int conv, const __bf16* __restrict__ zp) {
  __shared__ __bf16 As[128 * 64], Bs[128 * 64];
  int m0 = blockIdx.y * 128, n0 = blockIdx.x * 128;
  int tid = threadIdx.x, w = tid >> 6, l = tid & 63;
  int wr = w >> 1, wc = w & 1;
  f32x4 acc[4][4];
#pragma unroll
  for (int i = 0; i < 4; ++i)
#pragma unroll
    for (int j = 0; j < 4; ++j) acc[i][j] = {0.f, 0.f, 0.f, 0.f};

  for (int k0 = 0; k0 < K; k0 += 64) {
    if (conv)
      stage_tile_conv(A, m0, k0, zp, As, w, l);
    else
      stage_tile(A, (size_t)m0, C_DIM, k0, As, w, l);
    stage_tile(Bm, (size_t)n0, K, k0, Bs, w, l);
    __syncthreads();
#pragma unroll
    for (int ks = 0; ks < 2; ++ks) {
      bf16x8 af[4], bf_[4];
#pragma unroll
      for (int i = 0; i < 4; ++i) af[i] = read_frag(As, wr * 4 + i, ks, l);
#pragma unroll
      for (int j = 0; j < 4; ++j) bf_[j] = read_frag(Bs, wc * 4 + j, ks, l);
#pragma unroll
      for (int i = 0; i < 4; ++i)
#pragma unroll
        for (int j = 0; j < 4; ++j)
          acc[i][j] = __builtin_amdgcn_mfma_f32_16x16x32_bf16(af[i], bf_[j], acc[i][j], 0, 0, 0);
    }
    __syncthreads();
  }
#pragma unroll
  for (int i = 0; i < 4; ++i) {
    int mrow = m0 + wr * 64 + i * 16 + ((l >> 4) << 2);
#pragma unroll
    for (int j = 0; j < 4; ++j) {
      int ncol = n0 + wc * 64 + j * 16 + (l & 15);
      float* cp = C + (size_t)mrow * N + ncol;
#pragma unroll
      for (int r = 0; r < 4; ++r) cp[(size_t)r * N] = acc[i][j][r];
    }
  }
}

// ---------------- per-row top-10 HOT kernel: single-pass min-3 filter ----------------
// Key semantics identical to R3-R7: u64 key = (flip32(dif) << 32) | j, dif pinned via
// key_hi(). Per-lane min-3 (per-component min-3 merged exactly); candidates for
// extraction = per-lane min-2; m2 = smallest EXCLUDED key per lane. Extraction is
// provably exact iff wave_min(original m2) >= theta (same condition as the count
// check: any missed top-10 element is an excluded key < theta). No second pass.
__global__ __launch_bounds__(256) void k_topk(const float* __restrict__ gram,
                                              const float* __restrict__ sq,
                                              int* __restrict__ idxo,
                                              float* __restrict__ wo,
                                              int* __restrict__ flags) {
  int lb = blockIdx.y;
  const float* gramb = gram + (size_t)lb * T_DIM * T_DIM;
  const float* sqb = sq + (size_t)lb * T_DIM;
  int* idxb = idxo + (size_t)lb * T_DIM * KNB;
  float* wbp = wo + (size_t)lb * T_DIM * KNB;

  int row = blockIdx.x * 4 + (threadIdx.x >> 6);
  int lane = threadIdx.x & 63;
  float sqi = sqb[row];
  const float* g = gramb + (size_t)row * T_DIM;
  const f32x4* g4 = (const f32x4*)g;
  const f32x4* s4 = (const f32x4*)sqb;

  // Phase 1: 4 independent min-3 trackers, one per float4 component (ILP, no stash)
  unsigned long long p0[4], p1[4], p2[4];
#pragma unroll
  for (int q = 0; q < 4; ++q) { p0[q] = ~0ull; p1[q] = ~0ull; p2[q] = ~0ull; }
#pragma unroll 4
  for (int tq = 0; tq < 8; ++tq) {
    int i4 = lane + 64 * tq;
    f32x4 gv = g4[i4];
    f32x4 sv = s4[i4];
    unsigned bj = (unsigned)(i4 * 4);
#pragma unroll
    for (int e = 0; e < 4; ++e) {
      unsigned u = key_hi(sqi, sv[e], gv[e]);
      unsigned long long key = ((unsigned long long)u << 32) | (bj + e);
      unsigned long long t1 = (key > p0[e]) ? key : p0[e];
      p0[e] = (key < p0[e]) ? key : p0[e];
      unsigned long long t2 = (t1 > p1[e]) ? t1 : p1[e];
      p1[e] = (t1 < p1[e]) ? t1 : p1[e];
      p2[e] = (t2 < p2[e]) ? t2 : p2[e];
    }
  }
  // exact merge of 4 sorted triples -> per-lane min-3 (m0 <= m1 <= m2)
  unsigned long long m0 = p0[0], m1 = p1[0], m2 = p2[0];
#pragma unroll
  for (int q = 1; q < 4; ++q) {
    unsigned long long k0 = p0[q], k1 = p1[q], k2 = p2[q];
    // insert k0 into (m0,m1,m2)
    unsigned long long t1 = (k0 > m0) ? k0 : m0;
    m0 = (k0 < m0) ? k0 : m0;
    unsigned long long t2 = (t1 > m1) ? t1 : m1;
    m1 = (t1 < m1) ? t1 : m1;
    m2 = (t2 < m2) ? t2 : m2;
    // insert k1 (>= k0 >= new m0) into (m1,m2)
    unsigned long long t3 = (k1 > m1) ? k1 : m1;
    m1 = (k1 < m1) ? k1 : m1;
    m2 = (t3 < m2) ? t3 : m2;
    // insert k2 (>= k1 >= new m1) into m2
    m2 = (k2 < m2) ? k2 : m2;
  }
  unsigned long long excl = m2;  // smallest key NOT in the candidate set (per lane)

  // Phase 2: 10-round wave extract-min over the 128 candidates; write results
  unsigned long long theta = 0;
#pragma unroll
  for (int s = 0; s < KNB; ++s) {
    unsigned long long m = m0;
#pragma unroll
    for (int d = 1; d < 64; d <<= 1) {
      unsigned long long o = __shfl_xor(m, d, 64);
      m = (o < m) ? o : m;
    }
    unsigned long long bal = __ballot(m0 == m);
    int leader = (int)__builtin_ctzll(bal);
    if (lane == leader) { m0 = m1; m1 = ~0ull; }
    if (lane == 0) {
      int j = (int)(unsigned)(m & 0xffffffffull);
      unsigned su = (unsigned)(m >> 32);
      unsigned bits = (su & 0x80000000u) ? (su & 0x7fffffffu) : ~su;
      float dif = __uint_as_float(bits);
      float sqj = sqb[j];
      float num = 0.5f * (sqi + sqj - dif);
      float wv = num / (sqrtf(sqi) * sqrtf(sqj));
      idxb[row * KNB + s] = j;
      wbp[row * KNB + s] = wv;
    }
    theta = m;
  }

  // Phase 3 (in-register): wave-min of smallest excluded key vs theta
#pragma unroll
  for (int d = 1; d < 64; d <<= 1) {
    unsigned long long o = __shfl_xor(excl, d, 64);
    excl = (o < excl) ? o : excl;
  }
  if (excl < theta && lane == 0) flags[(size_t)lb * T_DIM + row] = 1;
}

// ---------------- FIX kernel: flagged rows only (rare), full sorted-10 insert ----------------
__global__ __launch_bounds__(256) void k_topk_fix(const float* __restrict__ gram,
                                                  const float* __restrict__ sq,
                                                  const int* __restrict__ flags,
                                                  int* __restrict__ idxo,
                                                  float* __restrict__ wo) {
  int lb = blockIdx.y;
  int row = blockIdx.x * 4 + (threadIdx.x >> 6);
  if (!flags[(size_t)lb * T_DIM + row]) return;  // wave-uniform
  const float* gramb = gram + (size_t)lb * T_DIM * T_DIM;
  const float* sqb = sq + (size_t)lb * T_DIM;
  int* idxb = idxo + (size_t)lb * T_DIM * KNB;
  float* wbp = wo + (size_t)lb * T_DIM * KNB;
  int lane = threadIdx.x & 63;
  float sqi = sqb[row];
  const float* g = gramb + (size_t)row * T_DIM;

  unsigned long long b0 = ~0ull, b1 = ~0ull, b2 = ~0ull, b3 = ~0ull, b4 = ~0ull,
                     b5 = ~0ull, b6 = ~0ull, b7 = ~0ull, b8 = ~0ull, b9 = ~0ull;
  for (int t = 0; t < 32; ++t) {
    unsigned j = (unsigned)(lane + 64 * t);
    unsigned u = key_hi(sqi, sqb[j], g[j]);
    unsigned long long key = ((unsigned long long)u << 32) | j;
    if (key < b9) {
      b9 = key;
      unsigned long long tt;
      if (b9 < b8) { tt = b8; b8 = b9; b9 = tt; }
      if (b8 < b7) { tt = b7; b7 = b8; b8 = tt; }
      if (b7 < b6) { tt = b6; b6 = b7; b7 = tt; }
      if (b6 < b5) { tt = b5; b5 = b6; b6 = tt; }
      if (b5 < b4) { tt = b4; b4 = b5; b5 = tt; }
      if (b4 < b3) { tt = b3; b3 = b4; b4 = tt; }
      if (b3 < b2) { tt = b2; b2 = b3; b3 = tt; }
      if (b2 < b1) { tt = b1; b1 = b2; b2 = tt; }
      if (b1 < b0) { tt = b0; b0 = b1; b1 = tt; }
    }
  }
#pragma unroll
  for (int s = 0; s < KNB; ++s) {
    unsigned long long m = b0;
#pragma unroll
    for (int d = 1; d < 64; d <<= 1) {
      unsigned long long o = __shfl_xor(m, d, 64);
      m = (o < m) ? o : m;
    }
    unsigned long long bal = __ballot(b0 == m);
    int leader = (int)__builtin_ctzll(bal);
    if (lane == leader) {
      b0 = b1; b1 = b2; b2 = b3; b3 = b4; b4 = b5;
      b5 = b6; b6 = b7; b7 = b8; b8 = b9; b9 = ~0ull;
    }
    if (lane == 0) {
      int j = (int)(unsigned)(m & 0xffffffffull);
      unsigned su = (unsigned)(m >> 32);
      unsigned bits = (su & 0x80000000u) ? (su & 0x7fffffffu) : ~su;
      float dif = __uint_as_float(bits);
      float sqj = sqb[j];
      float num = 0.5f * (sqi + sqj - dif);
      float wv = num / (sqrtf(sqi) * sqrtf(sqj));
      idxb[row * KNB + s] = j;
      wbp[row * KNB + s] = wv;
    }
  }
}

// ---------------- fused gmax + conv-bias + relu + pairwise maxpool + transpose ----------------
__global__ __launch_bounds__(256) void k_gfinal(const float* __restrict__ mlpout,
                                                const float* __restrict__ mlp_b,
                                                const int* __restrict__ idxo,
                                                const float* __restrict__ wo,
                                                const float* __restrict__ convb,
                                                const float* __restrict__ cb,
                                                float* __restrict__ out) {
  __shared__ float tile[32][33];
  __shared__ int sj[64][KNB];
  __shared__ float sw[64][KNB];
  int b = blockIdx.z, c0 = blockIdx.y * 32, t20 = blockIdx.x * 32;
  int tid = threadIdx.x;
  int nbase = b * T_DIM + t20 * 2;
  for (int e = tid; e < 64 * KNB; e += 256) {
    int ln = e / KNB, k = e - ln * KNB;
    sj[ln][k] = b * T_DIM + idxo[(size_t)(nbase + ln) * KNB + k];
    sw[ln][k] = wo[(size_t)(nbase + ln) * KNB + k];
  }
  __syncthreads();
  int tx = tid & 31, ty = tid >> 5;
  int c = c0 + tx;
  float bias_c = cb[c];
  float mbias = mlp_b[c];
#pragma unroll
  for (int rr = 0; rr < 4; ++rr) {
    int lt2 = ty + 8 * rr;
    float res[2];
#pragma unroll
    for (int s = 0; s < 2; ++s) {
      int ln = 2 * lt2 + s;
      int n = nbase + ln;
      float q = mlpout[(size_t)n * 512 + 256 + c] + mbias;
      float mx = -3.4e38f;
#pragma unroll
      for (int k = 0; k < KNB; ++k) {
        float v = (mlpout[(size_t)sj[ln][k] * 512 + c] + q) * sw[ln][k];
        mx = fmaxf(mx, v);
      }
      float v = convb[(size_t)n * C_DIM + c] + mx + bias_c;
      res[s] = fmaxf(v, 0.f);
    }
    tile[lt2][tx] = fmaxf(res[0], res[1]);
  }
  __syncthreads();
#pragma unroll
  for (int rr = 0; rr < 4; ++rr) {
    int cc = c0 + ty + 8 * rr;
    out[((size_t)b * C_DIM + cc) * (T_DIM / 2) + t20 + tx] = tile[tx][ty + 8 * rr];
  }
}

// ---------------- merged repack + flags zeroing ----------------
__global__ void k_repack(const float* __restrict__ cw, const float* __restrict__ mw,
                         __bf16* __restrict__ wk3, __bf16* __restrict__ mlpB,
                         __bf16* __restrict__ zp, int* __restrict__ flags) {
  int i = blockIdx.x * 256 + threadIdx.x;
  if (i < NPTS) flags[i] = 0;
  if (i < 3 * C_DIM * C_DIM) {
    int o = i / 768;
    int rem = i - o * 768;
    int tap = rem >> 8;
    int ii = rem & 255;
    wk3[i] = bfbits(f2bf_rn(cw[(size_t)o * 768 + ii * 3 + tap]));
  } else {
    int m = i - 3 * C_DIM * C_DIM;
    if (m < 512 * 256) {
      int r = m >> 8;
      int col = m & 255;
      mlpB[m] = bfbits(f2bf_rn(mw[(size_t)(r & 255) * 512 + ((r >> 8) << 8) + col]));
    }
  }
  if (blockIdx.x == 0 && threadIdx.x < 128) zp[threadIdx.x] = bfbits(0);
}

extern "C" void kernel_launch(void* const* d_in, const int* in_sizes, int n_in,
                              void* d_out, int out_size, void* d_ws, size_t ws_size,
                              hipStream_t stream) {
  const float* x = (const float*)d_in[0];
  const float* conv_w = (const float*)d_in[2];
  const float* conv_b = (const float*)d_in[3];
  const float* mlp_w = (const float*)d_in[4];
  const float* mlp_b = (const float*)d_in[5];
  float* out = (float*)d_out;

  char* ws = (char*)d_ws;
  size_t off = 0;
  auto alloc = [&](size_t bytes) -> void* {
    void* p = ws + off;
    off += (bytes + 255) & ~(size_t)255;
    return p;
  };
  float* gram = (float*)alloc((size_t)BS * T_DIM * T_DIM * 4);
  __bf16* Fh = (__bf16*)alloc((size_t)NPTS * C_DIM * 2);
  __bf16* Fl = (__bf16*)alloc((size_t)NPTS * C_DIM * 2);
  float* convout = (float*)alloc((size_t)NPTS * C_DIM * 4);
  float* mlpout = (float*)alloc((size_t)NPTS * 512 * 4);
  float* sq = (float*)alloc((size_t)NPTS * 4);
  int* idxb = (int*)alloc((size_t)NPTS * KNB * 4);
  float* wb = (float*)alloc((size_t)NPTS * KNB * 4);
  int* flags = (int*)alloc((size_t)NPTS * 4);
  __bf16* wk3 = (__bf16*)alloc((size_t)3 * C_DIM * C_DIM * 2);
  __bf16* mlpB = (__bf16*)alloc((size_t)512 * 256 * 2);
  __bf16* zp = (__bf16*)alloc(512);

  k_repack<<<dim3(1280), 256, 0, stream>>>(conv_w, mlp_w, wk3, mlpB, zp, flags);
  k_transpose_split<<<dim3(T_DIM / 32, C_DIM / 32, BS), 256, 0, stream>>>(x, Fh, Fl);
  k_sq<<<dim3(NPTS / 4), 256, 0, stream>>>(Fh, Fl, sq);

  k_gram_sym<<<dim3(136, BS), 256, 0, stream>>>(Fh, Fl, gram);
  k_topk<<<dim3(T_DIM / 4, BS), 256, 0, stream>>>(gram, sq, idxb, wb, flags);
  k_topk_fix<<<dim3(T_DIM / 4, BS), 256, 0, stream>>>(gram, sq, flags, idxb, wb);

  k_gemm16<<<dim3(512 / 128, NPTS / 128), 256, 0, stream>>>(Fh, mlpB, mlpout, 512, 256, 0, zp);
  k_gemm16<<<dim3(256 / 128, NPTS / 128), 256, 0, stream>>>(Fh, wk3, convout, 256, 768, 1, zp);

  k_gfinal<<<dim3((T_DIM / 2) / 32, C_DIM / 32, BS), 256, 0, stream>>>(
      mlpout, mlp_b, idxb, wb, convout, conv_b, out);
}

// Round 9
// 172.970 us; speedup vs baseline: 1.2892x; 1.0838x over previous
//
#include <hip/hip_runtime.h>
#include <hip/hip_bf16.h>
#include <cstdint>

#define T_DIM 2048
#define C_DIM 256
#define BS 8
#define NPTS (BS * T_DIM)
#define KNB 10

typedef __bf16 bf16x8 __attribute__((ext_vector_type(8)));
typedef float f32x4 __attribute__((ext_vector_type(4)));

#define AS1 __attribute__((address_space(1)))
#define AS3 __attribute__((address_space(3)))

__device__ __forceinline__ unsigned short f2bf_rn(float f) {
  unsigned u = __float_as_uint(f);
  unsigned r = (u + 0x7FFFu + ((u >> 16) & 1u)) >> 16;
  return (unsigned short)r;
}
__device__ __forceinline__ float bfbits2f(unsigned short h) {
  return __uint_as_float((unsigned)h << 16);
}
__device__ __forceinline__ __bf16 bfbits(unsigned short h) {
  return __builtin_bit_cast(__bf16, h);
}

// pinned dif computation: identical instruction sequence at every use site so
// hot-kernel keys, theta, and fix-kernel keys are bit-identical.
__device__ __forceinline__ unsigned key_hi(float sqi, float sqj, float gv) {
  float dif = __fmaf_rn(-2.0f, gv, __fadd_rn(sqi, sqj));
  unsigned u = __float_as_uint(dif);
  return (u & 0x80000000u) ? ~u : (u | 0x80000000u);
}

// ---- stage a 128x64 bf16 tile into XOR-swizzled LDS via global_load_lds ----
__device__ __forceinline__ void stage_tile(const __bf16* __restrict__ src, size_t row0,
                                           int ld, int k0, __bf16* lds, int w, int l) {
  int kofs = ((l & 7) ^ (l >> 3)) * 8;
  const __bf16* g0 = src + (row0 + (size_t)(l >> 3)) * ld + k0 + kofs;
  __bf16* lbase = lds + (size_t)(w * 4) * 512;
#pragma unroll
  for (int q4 = 0; q4 < 4; ++q4) {
    __builtin_amdgcn_global_load_lds((AS1 void*)(g0 + (size_t)(w * 4 + q4) * 8 * ld),
                                     (AS3 void*)(lbase + q4 * 512), 16, 0, 0);
  }
}

// conv im2col staging: K=768 = 3 taps x 256
__device__ __forceinline__ void stage_tile_conv(const __bf16* __restrict__ src, int m0,
                                                int k0in, const __bf16* __restrict__ zp,
                                                __bf16* lds, int w, int l) {
  int tap = k0in >> 8;
  int kshift = tap - 1;
  int k0 = k0in & 255;
  int kofs = ((l & 7) ^ (l >> 3)) * 8;
  int mb = m0 & (T_DIM - 1);
#pragma unroll
  for (int q4 = 0; q4 < 4; ++q4) {
    int q = w * 4 + q4;
    int row = q * 8 + (l >> 3);
    int t = mb + row + kshift;
    const __bf16* g = ((unsigned)t < (unsigned)T_DIM)
                          ? (src + (size_t)(m0 + row + kshift) * C_DIM + k0 + kofs)
                          : (zp + kofs);
    __builtin_amdgcn_global_load_lds((AS1 void*)g, (AS3 void*)(lds + q * 512), 16, 0, 0);
  }
}

__device__ __forceinline__ bf16x8 read_frag(const __bf16* lds, int t16, int ks, int l) {
  int row = t16 * 16 + (l & 15);
  int kb = ks * 64 + ((l >> 4) << 4);
  int byte = row * 128 + (kb ^ ((row & 7) << 4));
  return *(const bf16x8*)((const char*)lds + byte);
}

// ---------------- transpose + hi/lo bf16 split ----------------
__global__ __launch_bounds__(256) void k_transpose_split(const float* __restrict__ x,
                                                         __bf16* __restrict__ Fh,
                                                         __bf16* __restrict__ Fl) {
  __shared__ float tile[32][33];
  int b = blockIdx.z;
  int t0 = blockIdx.x * 32;
  int c0 = blockIdx.y * 32;
  int tx = threadIdx.x & 31, ty = threadIdx.x >> 5;
  const float* xb = x + (size_t)b * C_DIM * T_DIM;
#pragma unroll
  for (int r = 0; r < 4; ++r) {
    int c = c0 + ty + 8 * r;
    tile[ty + 8 * r][tx] = xb[(size_t)c * T_DIM + t0 + tx];
  }
  __syncthreads();
#pragma unroll
  for (int r = 0; r < 4; ++r) {
    int t = t0 + ty + 8 * r;
    float v = tile[tx][ty + 8 * r];
    unsigned short hb = f2bf_rn(v);
    float lo = v - bfbits2f(hb);
    size_t o = ((size_t)b * T_DIM + t) * C_DIM + c0 + tx;
    Fh[o] = bfbits(hb);
    Fl[o] = bfbits(f2bf_rn(lo));
  }
}

// ---------------- sq[n] = sum_c (hi+lo)^2 ----------------
__global__ __launch_bounds__(256) void k_sq(const __bf16* __restrict__ Fh,
                                            const __bf16* __restrict__ Fl,
                                            float* __restrict__ sq) {
  int n = blockIdx.x * 4 + (threadIdx.x >> 6);
  int lane = threadIdx.x & 63;
  ushort4 hv = ((const ushort4*)Fh)[(size_t)n * 64 + lane];
  ushort4 lv = ((const ushort4*)Fl)[(size_t)n * 64 + lane];
  float s = 0.f;
  {
    float v;
    v = bfbits2f(hv.x) + bfbits2f(lv.x); s = fmaf(v, v, s);
    v = bfbits2f(hv.y) + bfbits2f(lv.y); s = fmaf(v, v, s);
    v = bfbits2f(hv.z) + bfbits2f(lv.z); s = fmaf(v, v, s);
    v = bfbits2f(hv.w) + bfbits2f(lv.w); s = fmaf(v, v, s);
  }
#pragma unroll
  for (int d = 1; d < 64; d <<= 1) s += __shfl_xor(s, d, 64);
  if (lane == 0) sq[n] = s;
}

// ---------------- Gram via split-bf16 MFMA, symmetric ----------------
__global__ __launch_bounds__(256, 2) void k_gram_sym(const __bf16* __restrict__ Fh,
                                                     const __bf16* __restrict__ Fl,
                                                     float* __restrict__ gram) {
  __shared__ __align__(16) char smem[65536];
  __bf16* Ah = (__bf16*)smem;
  __bf16* Al = (__bf16*)(smem + 16384);
  __bf16* Bh = (__bf16*)(smem + 32768);
  __bf16* Bl = (__bf16*)(smem + 49152);

  int b = blockIdx.y;
  int ti = blockIdx.x;
  int by = (int)((sqrtf(8.0f * (float)ti + 1.0f) - 1.0f) * 0.5f);
  if ((by + 1) * (by + 2) / 2 <= ti) by++;
  int bx = ti - by * (by + 1) / 2;

  size_t base = (size_t)b * T_DIM;
  int m0 = by * 128, n0 = bx * 128;
  int tid = threadIdx.x, w = tid >> 6, l = tid & 63;
  int wr = w >> 1, wc = w & 1;
  f32x4 acc[4][4];
#pragma unroll
  for (int i = 0; i < 4; ++i)
#pragma unroll
    for (int j = 0; j < 4; ++j) acc[i][j] = {0.f, 0.f, 0.f, 0.f};

  for (int k0 = 0; k0 < C_DIM; k0 += 64) {
    stage_tile(Fh, base + m0, C_DIM, k0, Ah, w, l);
    stage_tile(Fl, base + m0, C_DIM, k0, Al, w, l);
    stage_tile(Fh, base + n0, C_DIM, k0, Bh, w, l);
    stage_tile(Fl, base + n0, C_DIM, k0, Bl, w, l);
    __syncthreads();
#pragma unroll
    for (int ks = 0; ks < 2; ++ks) {
      bf16x8 ah[4], bh[4], x[4];
#pragma unroll
      for (int i = 0; i < 4; ++i) ah[i] = read_frag(Ah, wr * 4 + i, ks, l);
#pragma unroll
      for (int j = 0; j < 4; ++j) bh[j] = read_frag(Bh, wc * 4 + j, ks, l);
#pragma unroll
      for (int i = 0; i < 4; ++i)
#pragma unroll
        for (int j = 0; j < 4; ++j)
          acc[i][j] = __builtin_amdgcn_mfma_f32_16x16x32_bf16(ah[i], bh[j], acc[i][j], 0, 0, 0);
#pragma unroll
      for (int i = 0; i < 4; ++i) x[i] = read_frag(Al, wr * 4 + i, ks, l);
#pragma unroll
      for (int i = 0; i < 4; ++i)
#pragma unroll
        for (int j = 0; j < 4; ++j)
          acc[i][j] = __builtin_amdgcn_mfma_f32_16x16x32_bf16(x[i], bh[j], acc[i][j], 0, 0, 0);
#pragma unroll
      for (int j = 0; j < 4; ++j) x[j] = read_frag(Bl, wc * 4 + j, ks, l);
#pragma unroll
      for (int i = 0; i < 4; ++i)
#pragma unroll
        for (int j = 0; j < 4; ++j)
          acc[i][j] = __builtin_amdgcn_mfma_f32_16x16x32_bf16(ah[i], x[j], acc[i][j], 0, 0, 0);
    }
    __syncthreads();
  }

  float* gout = gram + (size_t)b * T_DIM * T_DIM;
#pragma unroll
  for (int i = 0; i < 4; ++i) {
    int mrow = m0 + wr * 64 + i * 16 + ((l >> 4) << 2);
#pragma unroll
    for (int j = 0; j < 4; ++j) {
      int ncol = n0 + wc * 64 + j * 16 + (l & 15);
      float* cp = gout + (size_t)mrow * T_DIM + ncol;
#pragma unroll
      for (int r = 0; r < 4; ++r) cp[(size_t)r * T_DIM] = acc[i][j][r];
    }
  }

  if (bx != by) {
    float* Tbuf = (float*)smem;
#pragma unroll
    for (int h = 0; h < 2; ++h) {
      __syncthreads();
      if (wc == h) {
#pragma unroll
        for (int j = 0; j < 4; ++j) {
          int cH = j * 16 + (l & 15);
          float* dst = Tbuf + cH * 132 + wr * 64 + ((l >> 4) << 2);
#pragma unroll
          for (int i = 0; i < 4; ++i) *(f32x4*)(dst + i * 16) = acc[i][j];
        }
      }
      __syncthreads();
      int cH = tid >> 5;
      int c4 = (tid & 31) * 4;
#pragma unroll
      for (int p = 0; p < 8; ++p) {
        f32x4 v = *(const f32x4*)(Tbuf + (size_t)(p * 8 + cH) * 132 + c4);
        *(f32x4*)(gout + (size_t)(n0 + h * 64 + p * 8 + cH) * T_DIM + m0 + c4) = v;
      }
    }
  }
}

// ---------------- merged bf16 GEMM dispatch: blocks 0-3 MLP, 4-5 conv ----------------
__global__ __launch_bounds__(256, 2) void k_gemm_fused(const __bf16* __restrict__ Fh,
                                                       const __bf16* __restrict__ mlpB,
                                                       const __bf16* __restrict__ wk3,
                                                       float* __restrict__ mlpout,
                                                       float* __restrict__ convout,
                                                       const __bf16* __restrict__ zp) {
  __shared__ __bf16 As[128 * 64], Bs[128 * 64];
  int bx = blockIdx.x;
  const __bf16* Bm;
  float* C;
  int N, K, conv, n0;
  if (bx < 4) {
    Bm = mlpB; C = mlpout; N = 512; K = 256; conv = 0; n0 = bx * 128;
  } else {
    Bm = wk3; C = convout; N = 256; K = 768; conv = 1; n0 = (bx - 4) * 128;
  }
  int m0 = blockIdx.y * 128;
  int tid = threadIdx.x, w = tid >> 6, l = tid & 63;
  int wr = w >> 1, wc = w & 1;
  f32x4 acc[4][4];
#pragma unroll
  for (int i = 0; i < 4; ++i)
#pragma unroll
    for (int j = 0; j < 4; ++j) acc[i][j] = {0.f, 0.f, 0.f, 0.f};

  for (int k0 = 0; k0 < K; k0 += 64) {
    if (conv)
      stage_tile_conv(Fh, m0, k0, zp, As, w, l);
    else
      stage_tile(Fh, (size_t)m0, C_DIM, k0, As, w, l);
    stage_tile(Bm, (size_t)n0, K, k0, Bs, w, l);
    __syncthreads();
#pragma unroll
    for (int ks = 0; ks < 2; ++ks) {
      bf16x8 af[4], bf_[4];
#pragma unroll
      for (int i = 0; i < 4; ++i) af[i] = read_frag(As, wr * 4 + i, ks, l);
#pragma unroll
      for (int j = 0; j < 4; ++j) bf_[j] = read_frag(Bs, wc * 4 + j, ks, l);
#pragma unroll
      for (int i = 0; i < 4; ++i)
#pragma unroll
        for (int j = 0; j < 4; ++j)
          acc[i][j] = __builtin_amdgcn_mfma_f32_16x16x32_bf16(af[i], bf_[j], acc[i][j], 0, 0, 0);
    }
    __syncthreads();
  }
#pragma unroll
  for (int i = 0; i < 4; ++i) {
    int mrow = m0 + wr * 64 + i * 16 + ((l >> 4) << 2);
#pragma unroll
    for (int j = 0; j < 4; ++j) {
      int ncol = n0 + wc * 64 + j * 16 + (l & 15);
      float* cp = C + (size_t)mrow * N + ncol;
#pragma unroll
      for (int r = 0; r < 4; ++r) cp[(size_t)r * N] = acc[i][j][r];
    }
  }
}

// ---------------- per-row top-10 HOT kernel: min-3 filter + cheap extraction ----------------
// Key semantics identical to R3-R8: u64 key = (flip32(dif) << 32) | j, dif pinned via
// key_hi(). Winner search per round: u32 min-butterfly on hi word (v_min_u32), then
// u32 min-butterfly on lo among hi-matching lanes — winner u64 identical to u64 min
// (keys distinct). Winners kept in regs; lanes 0-9 compute w and store in parallel
// (output is order-invariant: reference takes max over k). Flag if any excluded key
// (wave-min of original m2) < theta.
__global__ __launch_bounds__(256) void k_topk(const float* __restrict__ gram,
                                              const float* __restrict__ sq,
                                              int* __restrict__ idxo,
                                              float* __restrict__ wo,
                                              int* __restrict__ flags) {
  int lb = blockIdx.y;
  const float* gramb = gram + (size_t)lb * T_DIM * T_DIM;
  const float* sqb = sq + (size_t)lb * T_DIM;
  int* idxb = idxo + (size_t)lb * T_DIM * KNB;
  float* wbp = wo + (size_t)lb * T_DIM * KNB;

  int row = blockIdx.x * 4 + (threadIdx.x >> 6);
  int lane = threadIdx.x & 63;
  float sqi = sqb[row];
  const float* g = gramb + (size_t)row * T_DIM;
  const f32x4* g4 = (const f32x4*)g;
  const f32x4* s4 = (const f32x4*)sqb;

  // Phase 1: 4 independent min-3 trackers, one per float4 component (ILP, no stash)
  unsigned long long p0[4], p1[4], p2[4];
#pragma unroll
  for (int q = 0; q < 4; ++q) { p0[q] = ~0ull; p1[q] = ~0ull; p2[q] = ~0ull; }
#pragma unroll 4
  for (int tq = 0; tq < 8; ++tq) {
    int i4 = lane + 64 * tq;
    f32x4 gv = g4[i4];
    f32x4 sv = s4[i4];
    unsigned bj = (unsigned)(i4 * 4);
#pragma unroll
    for (int e = 0; e < 4; ++e) {
      unsigned u = key_hi(sqi, sv[e], gv[e]);
      unsigned long long key = ((unsigned long long)u << 32) | (bj + e);
      unsigned long long t1 = (key > p0[e]) ? key : p0[e];
      p0[e] = (key < p0[e]) ? key : p0[e];
      unsigned long long t2 = (t1 > p1[e]) ? t1 : p1[e];
      p1[e] = (t1 < p1[e]) ? t1 : p1[e];
      p2[e] = (t2 < p2[e]) ? t2 : p2[e];
    }
  }
  // exact merge of 4 sorted triples -> per-lane min-3 (m0 <= m1 <= m2)
  unsigned long long m0 = p0[0], m1 = p1[0], m2 = p2[0];
#pragma unroll
  for (int q = 1; q < 4; ++q) {
    unsigned long long k0 = p0[q], k1 = p1[q], k2 = p2[q];
    unsigned long long t1 = (k0 > m0) ? k0 : m0;
    m0 = (k0 < m0) ? k0 : m0;
    unsigned long long t2 = (t1 > m1) ? t1 : m1;
    m1 = (t1 < m1) ? t1 : m1;
    m2 = (t2 < m2) ? t2 : m2;
    unsigned long long t3 = (k1 > m1) ? k1 : m1;
    m1 = (k1 < m1) ? k1 : m1;
    m2 = (t3 < m2) ? t3 : m2;
    m2 = (k2 < m2) ? k2 : m2;
  }
  unsigned long long excl = m2;  // smallest key NOT in the candidate set (per lane)

  // Phase 2: 10 rounds of cheap extract-min over the 128 candidates (winners in regs)
  unsigned long long win[KNB];
#pragma unroll
  for (int s = 0; s < KNB; ++s) {
    unsigned mh = (unsigned)(m0 >> 32);
    unsigned h = mh;
#pragma unroll
    for (int d = 1; d < 64; d <<= 1) {
      unsigned oh = __shfl_xor(h, d, 64);
      h = (oh < h) ? oh : h;
    }
    unsigned lo = (mh == h) ? (unsigned)m0 : 0xFFFFFFFFu;
#pragma unroll
    for (int d = 1; d < 64; d <<= 1) {
      unsigned ol = __shfl_xor(lo, d, 64);
      lo = (ol < lo) ? ol : lo;
    }
    unsigned long long m = ((unsigned long long)h << 32) | lo;
    win[s] = m;
    unsigned long long bal = __ballot(m0 == m);
    int leader = (int)__builtin_ctzll(bal);
    if (lane == leader) { m0 = m1; m1 = ~0ull; }
  }
  unsigned long long theta = win[KNB - 1];

  // Parallel epilogue: lane s takes winner s, computes w, stores (order-invariant)
  unsigned long long mywin = win[0];
#pragma unroll
  for (int s = 1; s < KNB; ++s) mywin = (lane == s) ? win[s] : mywin;
  if (lane < KNB) {
    int j = (int)(unsigned)(mywin & 0xffffffffull);
    unsigned su = (unsigned)(mywin >> 32);
    unsigned bits = (su & 0x80000000u) ? (su & 0x7fffffffu) : ~su;
    float dif = __uint_as_float(bits);
    float sqj = sqb[j];
    float num = 0.5f * (sqi + sqj - dif);
    float wv = num / (sqrtf(sqi) * sqrtf(sqj));
    idxb[row * KNB + lane] = j;
    wbp[row * KNB + lane] = wv;
  }

  // Phase 3 (in-register): wave-min of smallest excluded key vs theta
#pragma unroll
  for (int d = 1; d < 64; d <<= 1) {
    unsigned long long o = __shfl_xor(excl, d, 64);
    excl = (o < excl) ? o : excl;
  }
  if (excl < theta && lane == 0) flags[(size_t)lb * T_DIM + row] = 1;
}

// ---------------- FIX kernel: flagged rows only (rare), full sorted-10 insert ----------------
__global__ __launch_bounds__(256) void k_topk_fix(const float* __restrict__ gram,
                                                  const float* __restrict__ sq,
                                                  const int* __restrict__ flags,
                                                  int* __restrict__ idxo,
                                                  float* __restrict__ wo) {
  int lb = blockIdx.y;
  int row = blockIdx.x * 4 + (threadIdx.x >> 6);
  if (!flags[(size_t)lb * T_DIM + row]) return;  // wave-uniform
  const float* gramb = gram + (size_t)lb * T_DIM * T_DIM;
  const float* sqb = sq + (size_t)lb * T_DIM;
  int* idxb = idxo + (size_t)lb * T_DIM * KNB;
  float* wbp = wo + (size_t)lb * T_DIM * KNB;
  int lane = threadIdx.x & 63;
  float sqi = sqb[row];
  const float* g = gramb + (size_t)row * T_DIM;

  unsigned long long b0 = ~0ull, b1 = ~0ull, b2 = ~0ull, b3 = ~0ull, b4 = ~0ull,
                     b5 = ~0ull, b6 = ~0ull, b7 = ~0ull, b8 = ~0ull, b9 = ~0ull;
  for (int t = 0; t < 32; ++t) {
    unsigned j = (unsigned)(lane + 64 * t);
    unsigned u = key_hi(sqi, sqb[j], g[j]);
    unsigned long long key = ((unsigned long long)u << 32) | j;
    if (key < b9) {
      b9 = key;
      unsigned long long tt;
      if (b9 < b8) { tt = b8; b8 = b9; b9 = tt; }
      if (b8 < b7) { tt = b7; b7 = b8; b8 = tt; }
      if (b7 < b6) { tt = b6; b6 = b7; b7 = tt; }
      if (b6 < b5) { tt = b5; b5 = b6; b6 = tt; }
      if (b5 < b4) { tt = b4; b4 = b5; b5 = tt; }
      if (b4 < b3) { tt = b3; b3 = b4; b4 = tt; }
      if (b3 < b2) { tt = b2; b2 = b3; b3 = tt; }
      if (b2 < b1) { tt = b1; b1 = b2; b2 = tt; }
      if (b1 < b0) { tt = b0; b0 = b1; b1 = tt; }
    }
  }
#pragma unroll
  for (int s = 0; s < KNB; ++s) {
    unsigned long long m = b0;
#pragma unroll
    for (int d = 1; d < 64; d <<= 1) {
      unsigned long long o = __shfl_xor(m, d, 64);
      m = (o < m) ? o : m;
    }
    unsigned long long bal = __ballot(b0 == m);
    int leader = (int)__builtin_ctzll(bal);
    if (lane == leader) {
      b0 = b1; b1 = b2; b2 = b3; b3 = b4; b4 = b5;
      b5 = b6; b6 = b7; b7 = b8; b8 = b9; b9 = ~0ull;
    }
    if (lane == 0) {
      int j = (int)(unsigned)(m & 0xffffffffull);
      unsigned su = (unsigned)(m >> 32);
      unsigned bits = (su & 0x80000000u) ? (su & 0x7fffffffu) : ~su;
      float dif = __uint_as_float(bits);
      float sqj = sqb[j];
      float num = 0.5f * (sqi + sqj - dif);
      float wv = num / (sqrtf(sqi) * sqrtf(sqj));
      idxb[row * KNB + s] = j;
      wbp[row * KNB + s] = wv;
    }
  }
}

// ---------------- fused gmax + conv-bias + relu + pairwise maxpool + transpose ----------------
__global__ __launch_bounds__(256) void k_gfinal(const float* __restrict__ mlpout,
                                                const float* __restrict__ mlp_b,
                                                const int* __restrict__ idxo,
                                                const float* __restrict__ wo,
                                                const float* __restrict__ convb,
                                                const float* __restrict__ cb,
                                                float* __restrict__ out) {
  __shared__ float tile[32][33];
  __shared__ int sj[64][KNB];
  __shared__ float sw[64][KNB];
  int b = blockIdx.z, c0 = blockIdx.y * 32, t20 = blockIdx.x * 32;
  int tid = threadIdx.x;
  int nbase = b * T_DIM + t20 * 2;
  for (int e = tid; e < 64 * KNB; e += 256) {
    int ln = e / KNB, k = e - ln * KNB;
    sj[ln][k] = b * T_DIM + idxo[(size_t)(nbase + ln) * KNB + k];
    sw[ln][k] = wo[(size_t)(nbase + ln) * KNB + k];
  }
  __syncthreads();
  int tx = tid & 31, ty = tid >> 5;
  int c = c0 + tx;
  float bias_c = cb[c];
  float mbias = mlp_b[c];
#pragma unroll
  for (int rr = 0; rr < 4; ++rr) {
    int lt2 = ty + 8 * rr;
    float res[2];
#pragma unroll
    for (int s = 0; s < 2; ++s) {
      int ln = 2 * lt2 + s;
      int n = nbase + ln;
      float q = mlpout[(size_t)n * 512 + 256 + c] + mbias;
      float mx = -3.4e38f;
#pragma unroll
      for (int k = 0; k < KNB; ++k) {
        float v = (mlpout[(size_t)sj[ln][k] * 512 + c] + q) * sw[ln][k];
        mx = fmaxf(mx, v);
      }
      float v = convb[(size_t)n * C_DIM + c] + mx + bias_c;
      res[s] = fmaxf(v, 0.f);
    }
    tile[lt2][tx] = fmaxf(res[0], res[1]);
  }
  __syncthreads();
#pragma unroll
  for (int rr = 0; rr < 4; ++rr) {
    int cc = c0 + ty + 8 * rr;
    out[((size_t)b * C_DIM + cc) * (T_DIM / 2) + t20 + tx] = tile[tx][ty + 8 * rr];
  }
}

// ---------------- merged repack + flags zeroing ----------------
__global__ void k_repack(const float* __restrict__ cw, const float* __restrict__ mw,
                         __bf16* __restrict__ wk3, __bf16* __restrict__ mlpB,
                         __bf16* __restrict__ zp, int* __restrict__ flags) {
  int i = blockIdx.x * 256 + threadIdx.x;
  if (i < NPTS) flags[i] = 0;
  if (i < 3 * C_DIM * C_DIM) {
    int o = i / 768;
    int rem = i - o * 768;
    int tap = rem >> 8;
    int ii = rem & 255;
    wk3[i] = bfbits(f2bf_rn(cw[(size_t)o * 768 + ii * 3 + tap]));
  } else {
    int m = i - 3 * C_DIM * C_DIM;
    if (m < 512 * 256) {
      int r = m >> 8;
      int col = m & 255;
      mlpB[m] = bfbits(f2bf_rn(mw[(size_t)(r & 255) * 512 + ((r >> 8) << 8) + col]));
    }
  }
  if (blockIdx.x == 0 && threadIdx.x < 128) zp[threadIdx.x] = bfbits(0);
}

extern "C" void kernel_launch(void* const* d_in, const int* in_sizes, int n_in,
                              void* d_out, int out_size, void* d_ws, size_t ws_size,
                              hipStream_t stream) {
  const float* x = (const float*)d_in[0];
  const float* conv_w = (const float*)d_in[2];
  const float* conv_b = (const float*)d_in[3];
  const float* mlp_w = (const float*)d_in[4];
  const float* mlp_b = (const float*)d_in[5];
  float* out = (float*)d_out;

  char* ws = (char*)d_ws;
  size_t off = 0;
  auto alloc = [&](size_t bytes) -> void* {
    void* p = ws + off;
    off += (bytes + 255) & ~(size_t)255;
    return p;
  };
  float* gram = (float*)alloc((size_t)BS * T_DIM * T_DIM * 4);
  __bf16* Fh = (__bf16*)alloc((size_t)NPTS * C_DIM * 2);
  __bf16* Fl = (__bf16*)alloc((size_t)NPTS * C_DIM * 2);
  float* convout = (float*)alloc((size_t)NPTS * C_DIM * 4);
  float* mlpout = (float*)alloc((size_t)NPTS * 512 * 4);
  float* sq = (float*)alloc((size_t)NPTS * 4);
  int* idxb = (int*)alloc((size_t)NPTS * KNB * 4);
  float* wb = (float*)alloc((size_t)NPTS * KNB * 4);
  int* flags = (int*)alloc((size_t)NPTS * 4);
  __bf16* wk3 = (__bf16*)alloc((size_t)3 * C_DIM * C_DIM * 2);
  __bf16* mlpB = (__bf16*)alloc((size_t)512 * 256 * 2);
  __bf16* zp = (__bf16*)alloc(512);

  k_repack<<<dim3(1280), 256, 0, stream>>>(conv_w, mlp_w, wk3, mlpB, zp, flags);
  k_transpose_split<<<dim3(T_DIM / 32, C_DIM / 32, BS), 256, 0, stream>>>(x, Fh, Fl);
  k_sq<<<dim3(NPTS / 4), 256, 0, stream>>>(Fh, Fl, sq);

  k_gram_sym<<<dim3(136, BS), 256, 0, stream>>>(Fh, Fl, gram);
  k_topk<<<dim3(T_DIM / 4, BS), 256, 0, stream>>>(gram, sq, idxb, wb, flags);
  k_topk_fix<<<dim3(T_DIM / 4, BS), 256, 0, stream>>>(gram, sq, flags, idxb, wb);

  k_gemm_fused<<<dim3(6, NPTS / 128), 256, 0, stream>>>(Fh, mlpB, wk3, mlpout, convout, zp);

  k_gfinal<<<dim3((T_DIM / 2) / 32, C_DIM / 32, BS), 256, 0, stream>>>(
      mlpout, mlp_b, idxb, wb, convout, conv_b, out);
}